// Round 4
// baseline (12026.091 us; speedup 1.0000x reference)
//
#include <hip/hip_runtime.h>
#include <hip/hip_bf16.h>

#define V 50257
#define E 256
#define H 512
#define C 16
#define B 256
#define T 128

typedef _Float16 f16x8 __attribute__((ext_vector_type(8)));
typedef _Float16 f16x4 __attribute__((ext_vector_type(4)));
typedef float f32x4 __attribute__((ext_vector_type(4)));

__device__ __forceinline__ float sigm(float x) { return 1.0f / (1.0f + __expf(-x)); }

__device__ __forceinline__ void gload16(const _Float16* g, _Float16* l) {
  __builtin_amdgcn_global_load_lds((const __attribute__((address_space(1))) unsigned*)g,
                                   (__attribute__((address_space(3))) unsigned*)l, 16, 0, 0);
}

// ---------------- one-time: xs_h[t*B+b][:] = f16(emb[tokens[b][t]] @ Wproj + bproj) ----------------
__global__ __launch_bounds__(256) void k_emb(const int* __restrict__ tokens,
                                             const float* __restrict__ emb,
                                             const float* __restrict__ Wproj,
                                             const float* __restrict__ bproj,
                                             _Float16* __restrict__ xs_h) {
  __shared__ float elds[16][256];
  const int tid = threadIdx.x;
  const int r0 = blockIdx.x * 16;  // row r = t*B + b
#pragma unroll
  for (int i = 0; i < 16; ++i) {
    int r = r0 + i;
    int t = r >> 8, b = r & 255;
    int tok = tokens[b * T + t];
    elds[i][tid] = (tok == 0) ? 0.0f : emb[(size_t)tok * E + tid];  // padding_idx=0
  }
  __syncthreads();
  float acc0[16], acc1[16];
#pragma unroll
  for (int i = 0; i < 16; ++i) { acc0[i] = 0.0f; acc1[i] = 0.0f; }
  for (int k = 0; k < E; k += 4) {
    float w0[4], w1[4];
#pragma unroll
    for (int kk = 0; kk < 4; ++kk) {
      w0[kk] = Wproj[(k + kk) * H + tid];
      w1[kk] = Wproj[(k + kk) * H + tid + 256];
    }
#pragma unroll
    for (int i = 0; i < 16; ++i) {
      float4 e4 = *(const float4*)&elds[i][k];
      acc0[i] = fmaf(e4.x, w0[0], acc0[i]);
      acc0[i] = fmaf(e4.y, w0[1], acc0[i]);
      acc0[i] = fmaf(e4.z, w0[2], acc0[i]);
      acc0[i] = fmaf(e4.w, w0[3], acc0[i]);
      acc1[i] = fmaf(e4.x, w1[0], acc1[i]);
      acc1[i] = fmaf(e4.y, w1[1], acc1[i]);
      acc1[i] = fmaf(e4.z, w1[2], acc1[i]);
      acc1[i] = fmaf(e4.w, w1[3], acc1[i]);
    }
  }
  float bp0 = bproj[tid], bp1 = bproj[tid + 256];
#pragma unroll
  for (int i = 0; i < 16; ++i) {
    size_t r = (size_t)(r0 + i);
    xs_h[r * H + tid] = (_Float16)(acc0[i] + bp0);
    xs_h[r * H + tid + 256] = (_Float16)(acc1[i] + bp1);
  }
}

// ---------------- weight prep (once per call) ----------------
// Gate-interleaved layout: n' = (hh>>4)*64 + gate*16 + (hh&15); k2<512 -> Wih, else Whh.
__global__ __launch_bounds__(256) void k_cvt_wg(const float* __restrict__ Wih,
                                                const float* __restrict__ Whh,
                                                _Float16* __restrict__ WgT) {
  for (size_t i4 = ((size_t)blockIdx.x * 256 + threadIdx.x) * 4; i4 < (size_t)33554432;
       i4 += (size_t)gridDim.x * 1024) {
    size_t c = i4 >> 21;
    size_t rem = i4 & 2097151;
    size_t np = rem >> 10;  // n' 0..2047
    size_t k2 = rem & 1023;
    int gate = (int)((np >> 4) & 3);
    int hh = (int)(((np >> 6) << 4) | (np & 15));
    size_t n = (size_t)gate * 512 + hh;
    const float* src = (k2 < 512) ? (Wih + (c * 2048 + n) * 512 + k2)
                                  : (Whh + (c * 2048 + n) * 512 + (k2 - 512));
    float4 v = *(const float4*)src;
    f16x4 o;
    o[0] = (_Float16)v.x; o[1] = (_Float16)v.y; o[2] = (_Float16)v.z; o[3] = (_Float16)v.w;
    *(f16x4*)&WgT[i4] = o;
  }
}

// transpose [c][k][n] f32 -> [c][n][k] f16 (512x512 per c)
__global__ __launch_bounds__(256) void k_cvt_tr(const float* __restrict__ W,
                                                _Float16* __restrict__ WT) {
  __shared__ float tl[64][65];
  const int tid = threadIdx.x;
  const int c = blockIdx.z;
  const int k0 = blockIdx.y * 64, n0 = blockIdx.x * 64;
  const float* Wc = W + (size_t)c * 262144;
#pragma unroll
  for (int q = 0; q < 16; ++q) {
    int idx = q * 256 + tid;
    int r = idx >> 6, cc = idx & 63;
    tl[r][cc] = Wc[(size_t)(k0 + r) * 512 + n0 + cc];
  }
  __syncthreads();
  _Float16* WTc = WT + (size_t)c * 262144;
#pragma unroll
  for (int q = 0; q < 16; ++q) {
    int idx = q * 256 + tid;
    int rr = idx >> 6, cc = idx & 63;
    WTc[(size_t)(n0 + rr) * 512 + k0 + cc] = (_Float16)tl[cc][rr];
  }
}

// bsum in interleaved n' layout
__global__ __launch_bounds__(256) void k_bias(const float* __restrict__ bih,
                                              const float* __restrict__ bhh,
                                              float* __restrict__ bsum) {
  int i = blockIdx.x * 256 + threadIdx.x;
  if (i < C * 4 * H) {
    int c = i >> 11, np = i & 2047;
    int gate = (np >> 4) & 3;
    int hh = ((np >> 6) << 4) | (np & 15);
    int n = gate * 512 + hh;
    bsum[i] = bih[c * 2048 + n] + bhh[c * 2048 + n];
  }
}

// ---------------- percept + LN fused: 32x512 tile per block, K=512 ----------------
// grid (8 m-tiles, 16 c). A = xq [256][512] from global (prefetched); B = WpT[c] via LDS.
__global__ __launch_bounds__(256, 2) void k_pln(const _Float16* __restrict__ xq,
                                                const _Float16* __restrict__ WpT,
                                                const float* __restrict__ bp,
                                                const float* __restrict__ ln_g,
                                                const float* __restrict__ ln_b,
                                                _Float16* __restrict__ Pdst) {
  __shared__ _Float16 Bsl[512 * 64];  // 64 KB
  const int tid = threadIdx.x;
  const int w = tid >> 6, l = tid & 63;
  const int mt = blockIdx.x;  // 0..7
  const int c = blockIdx.y;   // 0..15
  const int m0 = mt * 32;
  const _Float16* Bb = WpT + (size_t)c * 262144;
  const int srow = l >> 3, sj = l & 7;
  const int lm = l & 15, lk = l >> 4;
  f32x4 acc[2][8];
#pragma unroll
  for (int i = 0; i < 2; ++i)
#pragma unroll
    for (int j = 0; j < 8; ++j) acc[i][j] = (f32x4)0.0f;
  const _Float16* pA0 = xq + (size_t)(m0 + lm) * 512 + lk * 8;
  const _Float16* pA1 = pA0 + 16 * 512;
  f16x8 a0s0 = *(const f16x8*)pA0;
  f16x8 a0s1 = *(const f16x8*)(pA0 + 32);
  f16x8 a1s0 = *(const f16x8*)pA1;
  f16x8 a1s1 = *(const f16x8*)(pA1 + 32);
#pragma unroll 1
  for (int kb = 0; kb < 8; ++kb) {
#pragma unroll
    for (int q = 0; q < 16; ++q) {
      int r = q * 32 + w * 8 + srow;
      int gj = sj ^ (r & 7);
      gload16(Bb + (size_t)r * 512 + kb * 64 + gj * 8, &Bsl[(q * 32 + w * 8) * 64]);
    }
    f16x8 u00 = a0s0, u01 = a0s1, u10 = a1s0, u11 = a1s1;
    if (kb < 7) {
      a0s0 = *(const f16x8*)(pA0 + (kb + 1) * 64);
      a0s1 = *(const f16x8*)(pA0 + (kb + 1) * 64 + 32);
      a1s0 = *(const f16x8*)(pA1 + (kb + 1) * 64);
      a1s1 = *(const f16x8*)(pA1 + (kb + 1) * 64 + 32);
    }
    __syncthreads();
#pragma unroll
    for (int s2 = 0; s2 < 2; ++s2) {
      f16x8 bf[8];
#pragma unroll
      for (int j = 0; j < 8; ++j) {
        int RN = w * 128 + j * 16 + lm;
        int pn = (s2 * 4 + lk) ^ (RN & 7);
        bf[j] = *(const f16x8*)&Bsl[RN * 64 + pn * 8];
      }
      f16x8 ua = s2 ? u01 : u00;
      f16x8 ub = s2 ? u11 : u10;
#pragma unroll
      for (int j = 0; j < 8; ++j) {
        acc[0][j] = __builtin_amdgcn_mfma_f32_16x16x32_f16(ua, bf[j], acc[0][j], 0, 0, 0);
        acc[1][j] = __builtin_amdgcn_mfma_f32_16x16x32_f16(ub, bf[j], acc[1][j], 0, 0, 0);
      }
    }
    __syncthreads();
  }
  // epilogue: bias + relu + LN over full 512-col rows
  float bv[8], gcol[8], bcol[8];
#pragma unroll
  for (int j = 0; j < 8; ++j) {
    int col = w * 128 + j * 16 + lm;
    bv[j] = bp[c * 512 + col];
    gcol[j] = ln_g[c * 512 + col];
    bcol[j] = ln_b[c * 512 + col];
  }
  float vals[2][8][4];
  float s1l[2][4], s2l[2][4];
#pragma unroll
  for (int i = 0; i < 2; ++i)
#pragma unroll
    for (int rg = 0; rg < 4; ++rg) { s1l[i][rg] = 0.0f; s2l[i][rg] = 0.0f; }
#pragma unroll
  for (int i = 0; i < 2; ++i)
#pragma unroll
    for (int j = 0; j < 8; ++j)
#pragma unroll
      for (int rg = 0; rg < 4; ++rg) {
        float v = fmaxf(acc[i][j][rg] + bv[j], 0.0f);
        vals[i][j][rg] = v;
        s1l[i][rg] += v;
        s2l[i][rg] += v * v;
      }
#pragma unroll
  for (int m = 1; m < 16; m <<= 1) {
#pragma unroll
    for (int i = 0; i < 2; ++i)
#pragma unroll
      for (int rg = 0; rg < 4; ++rg) {
        s1l[i][rg] += __shfl_xor(s1l[i][rg], m, 64);
        s2l[i][rg] += __shfl_xor(s2l[i][rg], m, 64);
      }
  }
  float* st = (float*)Bsl;  // reuse LDS for stats [w][32 rows][2]
  if (lm == 0) {
#pragma unroll
    for (int i = 0; i < 2; ++i)
#pragma unroll
      for (int rg = 0; rg < 4; ++rg) {
        int row = i * 16 + lk * 4 + rg;
        st[(w * 32 + row) * 2] = s1l[i][rg];
        st[(w * 32 + row) * 2 + 1] = s2l[i][rg];
      }
  }
  __syncthreads();
  float mu_[2][4], rs_[2][4];
#pragma unroll
  for (int i = 0; i < 2; ++i)
#pragma unroll
    for (int rg = 0; rg < 4; ++rg) {
      int row = i * 16 + lk * 4 + rg;
      float t1 = 0.0f, t2 = 0.0f;
#pragma unroll
      for (int ww = 0; ww < 4; ++ww) {
        t1 += st[(ww * 32 + row) * 2];
        t2 += st[(ww * 32 + row) * 2 + 1];
      }
      float mu = t1 * (1.0f / 512.0f);
      float var = t2 * (1.0f / 512.0f) - mu * mu;
      mu_[i][rg] = mu;
      rs_[i][rg] = rsqrtf(var + 1e-5f);
    }
#pragma unroll
  for (int i = 0; i < 2; ++i)
#pragma unroll
    for (int j = 0; j < 8; ++j) {
      int col = w * 128 + j * 16 + lm;
#pragma unroll
      for (int rg = 0; rg < 4; ++rg) {
        int row = i * 16 + lk * 4 + rg;
        float o = (vals[i][j][rg] - mu_[i][rg]) * rs_[i][rg] * gcol[j] + bcol[j];
        Pdst[((size_t)c * 256 + m0 + row) * 1024 + col] = (_Float16)o;
      }
    }
}

// ---------------- gates + LSTM fused: 128x128 tile, K=1024, interleaved gate cols ----------------
__global__ __launch_bounds__(256, 2) void k_gates(const _Float16* __restrict__ A,
                                                  const _Float16* __restrict__ Bm,
                                                  const float* __restrict__ bias,
                                                  float* __restrict__ cstate,
                                                  _Float16* __restrict__ hdst) {
  __shared__ _Float16 Asl[128 * 64];
  __shared__ _Float16 Bsl[128 * 64];
  const int tid = threadIdx.x;
  const int w = tid >> 6, l = tid & 63;
  const int c = blockIdx.z;
  const int m0 = blockIdx.y * 128, n0 = blockIdx.x * 128;
  const _Float16* Ab = A + (size_t)c * 262144 + (size_t)m0 * 1024;
  const _Float16* Bb = Bm + (size_t)c * 2097152 + (size_t)n0 * 1024;
  f32x4 acc[4][4];
#pragma unroll
  for (int i = 0; i < 4; ++i)
#pragma unroll
    for (int j = 0; j < 4; ++j) acc[i][j] = (f32x4)0.0f;
  const int wm = (w >> 1) * 64, wn = (w & 1) * 64;
  const int srow = l >> 3, sj = l & 7;
#pragma unroll 1
  for (int kb = 0; kb < 16; ++kb) {
#pragma unroll
    for (int q = 0; q < 4; ++q) {
      int r = w * 32 + q * 8 + srow;
      int gj = sj ^ (r & 7);
      gload16(Ab + (size_t)r * 1024 + kb * 64 + gj * 8, &Asl[(w * 32 + q * 8) * 64]);
      gload16(Bb + (size_t)r * 1024 + kb * 64 + gj * 8, &Bsl[(w * 32 + q * 8) * 64]);
    }
    __syncthreads();
#pragma unroll
    for (int s2 = 0; s2 < 2; ++s2) {
      f16x8 af[4], bf[4];
#pragma unroll
      for (int i = 0; i < 4; ++i) {
        int R = wm + i * 16 + (l & 15);
        int p = (s2 * 4 + (l >> 4)) ^ (R & 7);
        af[i] = *(const f16x8*)&Asl[R * 64 + p * 8];
        int RN = wn + i * 16 + (l & 15);
        int pn = (s2 * 4 + (l >> 4)) ^ (RN & 7);
        bf[i] = *(const f16x8*)&Bsl[RN * 64 + pn * 8];
      }
#pragma unroll
      for (int i = 0; i < 4; ++i)
#pragma unroll
        for (int j = 0; j < 4; ++j)
          acc[i][j] = __builtin_amdgcn_mfma_f32_16x16x32_f16(af[i], bf[j], acc[i][j], 0, 0, 0);
    }
    __syncthreads();
  }
  const int rl = (l >> 4) * 4, cl = l & 15;
  // columns n' = n0+wn + j*16 + cl : gate j of h-index hh
  const int hh = (((n0 + wn) >> 6) << 4) + cl;
  float bv[4];
#pragma unroll
  for (int j = 0; j < 4; ++j) bv[j] = bias[(size_t)c * 2048 + (n0 + wn) + j * 16 + cl];
#pragma unroll
  for (int i = 0; i < 4; ++i) {
#pragma unroll
    for (int rg = 0; rg < 4; ++rg) {
      int row = m0 + wm + i * 16 + rl + rg;
      float ig = acc[i][0][rg] + bv[0];
      float fg = acc[i][1][rg] + bv[1];
      float gg = acc[i][2][rg] + bv[2];
      float og = acc[i][3][rg] + bv[3];
      size_t ci = ((size_t)c * 256 + row) * 512 + hh;
      float cn = sigm(fg) * cstate[ci] + sigm(ig) * tanhf(gg);
      cstate[ci] = cn;
      hdst[((size_t)c * 256 + row) * 1024 + 512 + hh] = (_Float16)(sigm(og) * tanhf(cn));
    }
  }
}

// ---------------- assoc + agg fused: 64x128 tile; last block per region reduces ----------------
// grid (4 nt, 4 mt, 16 c). An = Aq-next base (h at cols 512..1023).
__global__ __launch_bounds__(256, 2) void k_assoc(const _Float16* __restrict__ An,
                                                  const _Float16* __restrict__ WaT,
                                                  const float* __restrict__ ba,
                                                  const float* __restrict__ gl,
                                                  _Float16* __restrict__ abuf,
                                                  unsigned* __restrict__ cnt,
                                                  const _Float16* __restrict__ xs_h,
                                                  _Float16* __restrict__ xq,
                                                  float* __restrict__ out, int t) {
  __shared__ _Float16 Asl[64 * 64];
  __shared__ _Float16 Bsl[128 * 64];
  __shared__ int lastFlag;
  const int tid = threadIdx.x;
  const int w = tid >> 6, l = tid & 63;
  const int nt = blockIdx.x, mt = blockIdx.y, c = blockIdx.z;
  const int n0 = nt * 128;
  const _Float16* Ab = An + 512 + ((size_t)c * 256 + mt * 64) * 1024;
  const _Float16* Bb = WaT + (size_t)c * 262144 + (size_t)n0 * 512;
  f32x4 acc[2][4];
#pragma unroll
  for (int i = 0; i < 2; ++i)
#pragma unroll
    for (int j = 0; j < 4; ++j) acc[i][j] = (f32x4)0.0f;
  const int wm = (w >> 1) * 32, wn = (w & 1) * 64;
  const int srow = l >> 3, sj = l & 7;
  const int lm = l & 15, lk = l >> 4;
#pragma unroll 1
  for (int kb = 0; kb < 8; ++kb) {
#pragma unroll
    for (int q = 0; q < 2; ++q) {
      int r = q * 32 + w * 8 + srow;
      int gj = sj ^ (r & 7);
      gload16(Ab + (size_t)r * 1024 + kb * 64 + gj * 8, &Asl[(q * 32 + w * 8) * 64]);
    }
#pragma unroll
    for (int q = 0; q < 4; ++q) {
      int r = q * 32 + w * 8 + srow;
      int gj = sj ^ (r & 7);
      gload16(Bb + (size_t)r * 512 + kb * 64 + gj * 8, &Bsl[(q * 32 + w * 8) * 64]);
    }
    __syncthreads();
#pragma unroll
    for (int s2 = 0; s2 < 2; ++s2) {
      f16x8 af[2], bf[4];
#pragma unroll
      for (int i = 0; i < 2; ++i) {
        int R = wm + i * 16 + lm;
        int p = (s2 * 4 + lk) ^ (R & 7);
        af[i] = *(const f16x8*)&Asl[R * 64 + p * 8];
      }
#pragma unroll
      for (int j = 0; j < 4; ++j) {
        int RN = wn + j * 16 + lm;
        int pn = (s2 * 4 + lk) ^ (RN & 7);
        bf[j] = *(const f16x8*)&Bsl[RN * 64 + pn * 8];
      }
#pragma unroll
      for (int i = 0; i < 2; ++i)
#pragma unroll
        for (int j = 0; j < 4; ++j)
          acc[i][j] = __builtin_amdgcn_mfma_f32_16x16x32_f16(af[i], bf[j], acc[i][j], 0, 0, 0);
    }
    __syncthreads();
  }
  float gv = sigm(gl[c]);
#pragma unroll
  for (int i = 0; i < 2; ++i)
#pragma unroll
    for (int j = 0; j < 4; ++j) {
      int gc = n0 + wn + j * 16 + lm;
      float bav = ba[c * 512 + gc];
#pragma unroll
      for (int rg = 0; rg < 4; ++rg) {
        int row = mt * 64 + wm + i * 16 + lk * 4 + rg;
        float v = tanhf(acc[i][j][rg] + bav) * gv;
        abuf[(size_t)c * 131072 + (size_t)row * 512 + gc] = (_Float16)v;
      }
    }
  // ---- last-block reduction over c for this (mt, nt) region ----
  __threadfence();
  __syncthreads();
  if (tid == 0) {
    unsigned old = atomicAdd(&cnt[t * 16 + mt * 4 + nt], 1u);
    lastFlag = (old == 15u);
  }
  __syncthreads();
  if (!lastFlag) return;
  __threadfence();
  const int br0 = mt * 64;
#pragma unroll 1
  for (int rnd = 0; rnd < 4; ++rnd) {
    int g = rnd * 256 + tid;       // elem-group of 8
    int row = g >> 4;              // 0..63
    int colg = (g & 15) * 8;       // 0..120
    size_t off = (size_t)(br0 + row) * 512 + n0 + colg;
    float s[8] = {0, 0, 0, 0, 0, 0, 0, 0};
#pragma unroll
    for (int cc = 0; cc < 16; ++cc) {
      f16x8 a = *(const f16x8*)&abuf[(size_t)cc * 131072 + off];
#pragma unroll
      for (int j = 0; j < 8; ++j) s[j] += (float)a[j];
    }
    float y[8];
#pragma unroll
    for (int j = 0; j < 8; ++j) y[j] = s[j] * (1.0f / 16.0f);
    int b = br0 + row, hcol = n0 + colg;
    float* op = &out[((size_t)b * T + t) * 512 + hcol];
    *(float4*)op = make_float4(y[0], y[1], y[2], y[3]);
    *(float4*)(op + 4) = make_float4(y[4], y[5], y[6], y[7]);
    if (t + 1 < T) {
      f16x8 xs4 = *(const f16x8*)&xs_h[(size_t)(t + 1) * 131072 + off];
      f16x8 xn;
#pragma unroll
      for (int j = 0; j < 8; ++j) xn[j] = (_Float16)((float)xs4[j] + 0.3f * y[j]);
      *(f16x8*)&xq[off] = xn;
    }
  }
}

extern "C" void kernel_launch(void* const* d_in, const int* in_sizes, int n_in,
                              void* d_out, int out_size, void* d_ws, size_t ws_size,
                              hipStream_t stream) {
  const int* tokens = (const int*)d_in[0];
  const float* emb = (const float*)d_in[1];
  const float* Wproj = (const float*)d_in[2];
  const float* bproj = (const float*)d_in[3];
  const float* Wp = (const float*)d_in[4];
  const float* bp = (const float*)d_in[5];
  const float* ln_g = (const float*)d_in[6];
  const float* ln_b = (const float*)d_in[7];
  const float* Wih = (const float*)d_in[8];
  const float* bih = (const float*)d_in[9];
  const float* Whh = (const float*)d_in[10];
  const float* bhh = (const float*)d_in[11];
  const float* Wa = (const float*)d_in[12];
  const float* ba = (const float*)d_in[13];
  const float* gl = (const float*)d_in[14];
  float* out = (float*)d_out;

  char* w8 = (char*)d_ws;
  _Float16* xs_h = (_Float16*)w8;                        // 33,554,432 B
  _Float16* Aq0 = (_Float16*)(w8 + 33554432);            // 16,777,216 B  [c][256][1024] P|h
  _Float16* Aq1 = (_Float16*)(w8 + 50331648);            // 16,777,216 B  ping-pong
  float* cbuf = (float*)(w8 + 67108864);                 //  8,388,608 B
  _Float16* abuf = (_Float16*)(w8 + 75497472);           //  4,194,304 B
  _Float16* xq = (_Float16*)(w8 + 79691776);             //    262,144 B
  _Float16* WpT = (_Float16*)(w8 + 79953920);            //  8,388,608 B
  _Float16* WaT = (_Float16*)(w8 + 88342528);            //  8,388,608 B
  _Float16* WgT = (_Float16*)(w8 + 96731136);            // 67,108,864 B
  float* bsum = (float*)(w8 + 163840000);                //    131,072 B (end 163,971,072)
  // cnt lives in the dead t=0 slice of xs_h (only read before the loop via the xq copy)
  unsigned* cnt = (unsigned*)w8;                         //      8,192 B (128 t x 16 regions)

  hipMemsetAsync(Aq0, 0, 16777216, stream);  // h0 = 0 (step 0 reads Aq0 h-region)
  hipMemsetAsync(cbuf, 0, 8388608, stream);  // c0 = 0

  k_cvt_wg<<<4096, 256, 0, stream>>>(Wih, Whh, WgT);
  k_cvt_tr<<<dim3(8, 8, 16), 256, 0, stream>>>(Wp, WpT);
  k_cvt_tr<<<dim3(8, 8, 16), 256, 0, stream>>>(Wa, WaT);
  k_bias<<<128, 256, 0, stream>>>(bih, bhh, bsum);
  k_emb<<<T * B / 16, 256, 0, stream>>>(tokens, emb, Wproj, bproj, xs_h);
  hipMemcpyAsync(xq, xs_h, 262144, hipMemcpyDeviceToDevice, stream);  // x0 (ext=0)
  hipMemsetAsync(cnt, 0, 8192, stream);  // AFTER k_emb + copy (overlaps xs_h slice 0)

  for (int t = 0; t < T; ++t) {
    _Float16* Ac = (t & 1) ? Aq1 : Aq0;  // P written here; holds h from t-1
    _Float16* An = (t & 1) ? Aq0 : Aq1;  // new h written here
    k_pln<<<dim3(8, 16), 256, 0, stream>>>(xq, WpT, bp, ln_g, ln_b, Ac);
    k_gates<<<dim3(16, 2, 16), 256, 0, stream>>>(Ac, WgT, bsum, cbuf, An);
    k_assoc<<<dim3(4, 4, 16), 256, 0, stream>>>(An, WaT, ba, gl, abuf, cnt, xs_h, xq, out, t);
  }
}

// Round 6
// 8433.445 us; speedup vs baseline: 1.4260x; 1.4260x over previous
//
#include <hip/hip_runtime.h>
#include <hip/hip_bf16.h>

#define V 50257
#define E 256
#define H 512
#define C 16
#define B 256
#define T 128

typedef _Float16 f16x8 __attribute__((ext_vector_type(8)));
typedef _Float16 f16x4 __attribute__((ext_vector_type(4)));
typedef float f32x4 __attribute__((ext_vector_type(4)));

__device__ __forceinline__ float sigm(float x) { return 1.0f / (1.0f + __expf(-x)); }

__device__ __forceinline__ void gload16(const _Float16* g, _Float16* l) {
  __builtin_amdgcn_global_load_lds((const __attribute__((address_space(1))) unsigned*)g,
                                   (__attribute__((address_space(3))) unsigned*)l, 16, 0, 0);
}

// ---------------- one-time: xs_h[t*B+b][:] = f16(emb[tokens[b][t]] @ Wproj + bproj) ----------------
__global__ __launch_bounds__(256) void k_emb(const int* __restrict__ tokens,
                                             const float* __restrict__ emb,
                                             const float* __restrict__ Wproj,
                                             const float* __restrict__ bproj,
                                             _Float16* __restrict__ xs_h) {
  __shared__ float elds[16][256];
  const int tid = threadIdx.x;
  const int r0 = blockIdx.x * 16;  // row r = t*B + b
#pragma unroll
  for (int i = 0; i < 16; ++i) {
    int r = r0 + i;
    int t = r >> 8, b = r & 255;
    int tok = tokens[b * T + t];
    elds[i][tid] = (tok == 0) ? 0.0f : emb[(size_t)tok * E + tid];  // padding_idx=0
  }
  __syncthreads();
  float acc0[16], acc1[16];
#pragma unroll
  for (int i = 0; i < 16; ++i) { acc0[i] = 0.0f; acc1[i] = 0.0f; }
  for (int k = 0; k < E; k += 4) {
    float w0[4], w1[4];
#pragma unroll
    for (int kk = 0; kk < 4; ++kk) {
      w0[kk] = Wproj[(k + kk) * H + tid];
      w1[kk] = Wproj[(k + kk) * H + tid + 256];
    }
#pragma unroll
    for (int i = 0; i < 16; ++i) {
      float4 e4 = *(const float4*)&elds[i][k];
      acc0[i] = fmaf(e4.x, w0[0], acc0[i]);
      acc0[i] = fmaf(e4.y, w0[1], acc0[i]);
      acc0[i] = fmaf(e4.z, w0[2], acc0[i]);
      acc0[i] = fmaf(e4.w, w0[3], acc0[i]);
      acc1[i] = fmaf(e4.x, w1[0], acc1[i]);
      acc1[i] = fmaf(e4.y, w1[1], acc1[i]);
      acc1[i] = fmaf(e4.z, w1[2], acc1[i]);
      acc1[i] = fmaf(e4.w, w1[3], acc1[i]);
    }
  }
  float bp0 = bproj[tid], bp1 = bproj[tid + 256];
#pragma unroll
  for (int i = 0; i < 16; ++i) {
    size_t r = (size_t)(r0 + i);
    xs_h[r * H + tid] = (_Float16)(acc0[i] + bp0);
    xs_h[r * H + tid + 256] = (_Float16)(acc1[i] + bp1);
  }
}

// ---------------- weight prep (once per call) ----------------
// Gate-interleaved layout: n' = (hh>>4)*64 + gate*16 + (hh&15); k2<512 -> Wih, else Whh.
__global__ __launch_bounds__(256) void k_cvt_wg(const float* __restrict__ Wih,
                                                const float* __restrict__ Whh,
                                                _Float16* __restrict__ WgT) {
  for (size_t i4 = ((size_t)blockIdx.x * 256 + threadIdx.x) * 4; i4 < (size_t)33554432;
       i4 += (size_t)gridDim.x * 1024) {
    size_t c = i4 >> 21;
    size_t rem = i4 & 2097151;
    size_t np = rem >> 10;  // n' 0..2047
    size_t k2 = rem & 1023;
    int gate = (int)((np >> 4) & 3);
    int hh = (int)(((np >> 6) << 4) | (np & 15));
    size_t n = (size_t)gate * 512 + hh;
    const float* src = (k2 < 512) ? (Wih + (c * 2048 + n) * 512 + k2)
                                  : (Whh + (c * 2048 + n) * 512 + (k2 - 512));
    float4 v = *(const float4*)src;
    f16x4 o;
    o[0] = (_Float16)v.x; o[1] = (_Float16)v.y; o[2] = (_Float16)v.z; o[3] = (_Float16)v.w;
    *(f16x4*)&WgT[i4] = o;
  }
}

// transpose [c][k][n] f32 -> [c][n][k] f16 (512x512 per c)
__global__ __launch_bounds__(256) void k_cvt_tr(const float* __restrict__ W,
                                                _Float16* __restrict__ WT) {
  __shared__ float tl[64][65];
  const int tid = threadIdx.x;
  const int c = blockIdx.z;
  const int k0 = blockIdx.y * 64, n0 = blockIdx.x * 64;
  const float* Wc = W + (size_t)c * 262144;
#pragma unroll
  for (int q = 0; q < 16; ++q) {
    int idx = q * 256 + tid;
    int r = idx >> 6, cc = idx & 63;
    tl[r][cc] = Wc[(size_t)(k0 + r) * 512 + n0 + cc];
  }
  __syncthreads();
  _Float16* WTc = WT + (size_t)c * 262144;
#pragma unroll
  for (int q = 0; q < 16; ++q) {
    int idx = q * 256 + tid;
    int rr = idx >> 6, cc = idx & 63;
    WTc[(size_t)(n0 + rr) * 512 + k0 + cc] = (_Float16)tl[cc][rr];
  }
}

// bsum in interleaved n' layout
__global__ __launch_bounds__(256) void k_bias(const float* __restrict__ bih,
                                              const float* __restrict__ bhh,
                                              float* __restrict__ bsum) {
  int i = blockIdx.x * 256 + threadIdx.x;
  if (i < C * 4 * H) {
    int c = i >> 11, np = i & 2047;
    int gate = (np >> 4) & 3;
    int hh = ((np >> 6) << 4) | (np & 15);
    int n = gate * 512 + hh;
    bsum[i] = bih[c * 2048 + n] + bhh[c * 2048 + n];
  }
}

// ---------------- percept + LN fused: 32x512 tile per block, K=512 ----------------
// grid (8 m-tiles, 16 c). A = xq [256][512] from global (prefetched); B = WpT[c] via LDS.
__global__ __launch_bounds__(256, 2) void k_pln(const _Float16* __restrict__ xq,
                                                const _Float16* __restrict__ WpT,
                                                const float* __restrict__ bp,
                                                const float* __restrict__ ln_g,
                                                const float* __restrict__ ln_b,
                                                _Float16* __restrict__ Pdst) {
  __shared__ _Float16 Bsl[512 * 64];  // 64 KB
  const int tid = threadIdx.x;
  const int w = tid >> 6, l = tid & 63;
  const int mt = blockIdx.x;  // 0..7
  const int c = blockIdx.y;   // 0..15
  const int m0 = mt * 32;
  const _Float16* Bb = WpT + (size_t)c * 262144;
  const int srow = l >> 3, sj = l & 7;
  const int lm = l & 15, lk = l >> 4;
  f32x4 acc[2][8];
#pragma unroll
  for (int i = 0; i < 2; ++i)
#pragma unroll
    for (int j = 0; j < 8; ++j) acc[i][j] = (f32x4)0.0f;
  const _Float16* pA0 = xq + (size_t)(m0 + lm) * 512 + lk * 8;
  const _Float16* pA1 = pA0 + 16 * 512;
  f16x8 a0s0 = *(const f16x8*)pA0;
  f16x8 a0s1 = *(const f16x8*)(pA0 + 32);
  f16x8 a1s0 = *(const f16x8*)pA1;
  f16x8 a1s1 = *(const f16x8*)(pA1 + 32);
#pragma unroll 1
  for (int kb = 0; kb < 8; ++kb) {
#pragma unroll
    for (int q = 0; q < 16; ++q) {
      int r = q * 32 + w * 8 + srow;
      int gj = sj ^ (r & 7);
      gload16(Bb + (size_t)r * 512 + kb * 64 + gj * 8, &Bsl[(q * 32 + w * 8) * 64]);
    }
    f16x8 u00 = a0s0, u01 = a0s1, u10 = a1s0, u11 = a1s1;
    if (kb < 7) {
      a0s0 = *(const f16x8*)(pA0 + (kb + 1) * 64);
      a0s1 = *(const f16x8*)(pA0 + (kb + 1) * 64 + 32);
      a1s0 = *(const f16x8*)(pA1 + (kb + 1) * 64);
      a1s1 = *(const f16x8*)(pA1 + (kb + 1) * 64 + 32);
    }
    __syncthreads();
#pragma unroll
    for (int s2 = 0; s2 < 2; ++s2) {
      f16x8 bf[8];
#pragma unroll
      for (int j = 0; j < 8; ++j) {
        int RN = w * 128 + j * 16 + lm;
        int pn = (s2 * 4 + lk) ^ (RN & 7);
        bf[j] = *(const f16x8*)&Bsl[RN * 64 + pn * 8];
      }
      f16x8 ua = s2 ? u01 : u00;
      f16x8 ub = s2 ? u11 : u10;
#pragma unroll
      for (int j = 0; j < 8; ++j) {
        acc[0][j] = __builtin_amdgcn_mfma_f32_16x16x32_f16(ua, bf[j], acc[0][j], 0, 0, 0);
        acc[1][j] = __builtin_amdgcn_mfma_f32_16x16x32_f16(ub, bf[j], acc[1][j], 0, 0, 0);
      }
    }
    __syncthreads();
  }
  // epilogue: bias + relu + LN over full 512-col rows
  float bv[8], gcol[8], bcol[8];
#pragma unroll
  for (int j = 0; j < 8; ++j) {
    int col = w * 128 + j * 16 + lm;
    bv[j] = bp[c * 512 + col];
    gcol[j] = ln_g[c * 512 + col];
    bcol[j] = ln_b[c * 512 + col];
  }
  float vals[2][8][4];
  float s1l[2][4], s2l[2][4];
#pragma unroll
  for (int i = 0; i < 2; ++i)
#pragma unroll
    for (int rg = 0; rg < 4; ++rg) { s1l[i][rg] = 0.0f; s2l[i][rg] = 0.0f; }
#pragma unroll
  for (int i = 0; i < 2; ++i)
#pragma unroll
    for (int j = 0; j < 8; ++j)
#pragma unroll
      for (int rg = 0; rg < 4; ++rg) {
        float v = fmaxf(acc[i][j][rg] + bv[j], 0.0f);
        vals[i][j][rg] = v;
        s1l[i][rg] += v;
        s2l[i][rg] += v * v;
      }
#pragma unroll
  for (int m = 1; m < 16; m <<= 1) {
#pragma unroll
    for (int i = 0; i < 2; ++i)
#pragma unroll
      for (int rg = 0; rg < 4; ++rg) {
        s1l[i][rg] += __shfl_xor(s1l[i][rg], m, 64);
        s2l[i][rg] += __shfl_xor(s2l[i][rg], m, 64);
      }
  }
  float* st = (float*)Bsl;  // reuse LDS for stats [w][32 rows][2]
  if (lm == 0) {
#pragma unroll
    for (int i = 0; i < 2; ++i)
#pragma unroll
      for (int rg = 0; rg < 4; ++rg) {
        int row = i * 16 + lk * 4 + rg;
        st[(w * 32 + row) * 2] = s1l[i][rg];
        st[(w * 32 + row) * 2 + 1] = s2l[i][rg];
      }
  }
  __syncthreads();
  float mu_[2][4], rs_[2][4];
#pragma unroll
  for (int i = 0; i < 2; ++i)
#pragma unroll
    for (int rg = 0; rg < 4; ++rg) {
      int row = i * 16 + lk * 4 + rg;
      float t1 = 0.0f, t2 = 0.0f;
#pragma unroll
      for (int ww = 0; ww < 4; ++ww) {
        t1 += st[(ww * 32 + row) * 2];
        t2 += st[(ww * 32 + row) * 2 + 1];
      }
      float mu = t1 * (1.0f / 512.0f);
      float var = t2 * (1.0f / 512.0f) - mu * mu;
      mu_[i][rg] = mu;
      rs_[i][rg] = rsqrtf(var + 1e-5f);
    }
#pragma unroll
  for (int i = 0; i < 2; ++i)
#pragma unroll
    for (int j = 0; j < 8; ++j) {
      int col = w * 128 + j * 16 + lm;
#pragma unroll
      for (int rg = 0; rg < 4; ++rg) {
        int row = i * 16 + lk * 4 + rg;
        float o = (vals[i][j][rg] - mu_[i][rg]) * rs_[i][rg] * gcol[j] + bcol[j];
        Pdst[((size_t)c * 256 + m0 + row) * 1024 + col] = (_Float16)o;
      }
    }
}

// ---------------- gates + LSTM fused: 128x128 tile, K=1024, interleaved gate cols ----------------
__global__ __launch_bounds__(256, 2) void k_gates(const _Float16* __restrict__ A,
                                                  const _Float16* __restrict__ Bm,
                                                  const float* __restrict__ bias,
                                                  float* __restrict__ cstate,
                                                  _Float16* __restrict__ hdst) {
  __shared__ _Float16 Asl[128 * 64];
  __shared__ _Float16 Bsl[128 * 64];
  const int tid = threadIdx.x;
  const int w = tid >> 6, l = tid & 63;
  const int c = blockIdx.z;
  const int m0 = blockIdx.y * 128, n0 = blockIdx.x * 128;
  const _Float16* Ab = A + (size_t)c * 262144 + (size_t)m0 * 1024;
  const _Float16* Bb = Bm + (size_t)c * 2097152 + (size_t)n0 * 1024;
  f32x4 acc[4][4];
#pragma unroll
  for (int i = 0; i < 4; ++i)
#pragma unroll
    for (int j = 0; j < 4; ++j) acc[i][j] = (f32x4)0.0f;
  const int wm = (w >> 1) * 64, wn = (w & 1) * 64;
  const int srow = l >> 3, sj = l & 7;
#pragma unroll 1
  for (int kb = 0; kb < 16; ++kb) {
#pragma unroll
    for (int q = 0; q < 4; ++q) {
      int r = w * 32 + q * 8 + srow;
      int gj = sj ^ (r & 7);
      gload16(Ab + (size_t)r * 1024 + kb * 64 + gj * 8, &Asl[(w * 32 + q * 8) * 64]);
      gload16(Bb + (size_t)r * 1024 + kb * 64 + gj * 8, &Bsl[(w * 32 + q * 8) * 64]);
    }
    __syncthreads();
#pragma unroll
    for (int s2 = 0; s2 < 2; ++s2) {
      f16x8 af[4], bf[4];
#pragma unroll
      for (int i = 0; i < 4; ++i) {
        int R = wm + i * 16 + (l & 15);
        int p = (s2 * 4 + (l >> 4)) ^ (R & 7);
        af[i] = *(const f16x8*)&Asl[R * 64 + p * 8];
        int RN = wn + i * 16 + (l & 15);
        int pn = (s2 * 4 + (l >> 4)) ^ (RN & 7);
        bf[i] = *(const f16x8*)&Bsl[RN * 64 + pn * 8];
      }
#pragma unroll
      for (int i = 0; i < 4; ++i)
#pragma unroll
        for (int j = 0; j < 4; ++j)
          acc[i][j] = __builtin_amdgcn_mfma_f32_16x16x32_f16(af[i], bf[j], acc[i][j], 0, 0, 0);
    }
    __syncthreads();
  }
  const int rl = (l >> 4) * 4, cl = l & 15;
  // columns n' = n0+wn + j*16 + cl : gate j of h-index hh
  const int hh = (((n0 + wn) >> 6) << 4) + cl;
  float bv[4];
#pragma unroll
  for (int j = 0; j < 4; ++j) bv[j] = bias[(size_t)c * 2048 + (n0 + wn) + j * 16 + cl];
#pragma unroll
  for (int i = 0; i < 4; ++i) {
#pragma unroll
    for (int rg = 0; rg < 4; ++rg) {
      int row = m0 + wm + i * 16 + rl + rg;
      float ig = acc[i][0][rg] + bv[0];
      float fg = acc[i][1][rg] + bv[1];
      float gg = acc[i][2][rg] + bv[2];
      float og = acc[i][3][rg] + bv[3];
      size_t ci = ((size_t)c * 256 + row) * 512 + hh;
      float cn = sigm(fg) * cstate[ci] + sigm(ig) * tanhf(gg);
      cstate[ci] = cn;
      hdst[((size_t)c * 256 + row) * 1024 + 512 + hh] = (_Float16)(sigm(og) * tanhf(cn));
    }
  }
}

// ---------------- assoc: 64x128 tile, plain epilogue (no fences/atomics) ----------------
// grid (4 nt, 4 mt, 16 c). An = Aq-next base (h at cols 512..1023).
__global__ __launch_bounds__(256, 2) void k_assoc(const _Float16* __restrict__ An,
                                                  const _Float16* __restrict__ WaT,
                                                  const float* __restrict__ ba,
                                                  const float* __restrict__ gl,
                                                  _Float16* __restrict__ abuf) {
  __shared__ _Float16 Asl[64 * 64];
  __shared__ _Float16 Bsl[128 * 64];
  const int tid = threadIdx.x;
  const int w = tid >> 6, l = tid & 63;
  const int nt = blockIdx.x, mt = blockIdx.y, c = blockIdx.z;
  const int n0 = nt * 128;
  const _Float16* Ab = An + 512 + ((size_t)c * 256 + mt * 64) * 1024;
  const _Float16* Bb = WaT + (size_t)c * 262144 + (size_t)n0 * 512;
  f32x4 acc[2][4];
#pragma unroll
  for (int i = 0; i < 2; ++i)
#pragma unroll
    for (int j = 0; j < 4; ++j) acc[i][j] = (f32x4)0.0f;
  const int wm = (w >> 1) * 32, wn = (w & 1) * 64;
  const int srow = l >> 3, sj = l & 7;
  const int lm = l & 15, lk = l >> 4;
#pragma unroll 1
  for (int kb = 0; kb < 8; ++kb) {
#pragma unroll
    for (int q = 0; q < 2; ++q) {
      int r = q * 32 + w * 8 + srow;
      int gj = sj ^ (r & 7);
      gload16(Ab + (size_t)r * 1024 + kb * 64 + gj * 8, &Asl[(q * 32 + w * 8) * 64]);
    }
#pragma unroll
    for (int q = 0; q < 4; ++q) {
      int r = q * 32 + w * 8 + srow;
      int gj = sj ^ (r & 7);
      gload16(Bb + (size_t)r * 512 + kb * 64 + gj * 8, &Bsl[(q * 32 + w * 8) * 64]);
    }
    __syncthreads();
#pragma unroll
    for (int s2 = 0; s2 < 2; ++s2) {
      f16x8 af[2], bf[4];
#pragma unroll
      for (int i = 0; i < 2; ++i) {
        int R = wm + i * 16 + lm;
        int p = (s2 * 4 + lk) ^ (R & 7);
        af[i] = *(const f16x8*)&Asl[R * 64 + p * 8];
      }
#pragma unroll
      for (int j = 0; j < 4; ++j) {
        int RN = wn + j * 16 + lm;
        int pn = (s2 * 4 + lk) ^ (RN & 7);
        bf[j] = *(const f16x8*)&Bsl[RN * 64 + pn * 8];
      }
#pragma unroll
      for (int i = 0; i < 2; ++i)
#pragma unroll
        for (int j = 0; j < 4; ++j)
          acc[i][j] = __builtin_amdgcn_mfma_f32_16x16x32_f16(af[i], bf[j], acc[i][j], 0, 0, 0);
    }
    __syncthreads();
  }
  float gv = sigm(gl[c]);
#pragma unroll
  for (int i = 0; i < 2; ++i)
#pragma unroll
    for (int j = 0; j < 4; ++j) {
      int gc = n0 + wn + j * 16 + lm;
      float bav = ba[c * 512 + gc];
#pragma unroll
      for (int rg = 0; rg < 4; ++rg) {
        int row = mt * 64 + wm + i * 16 + lk * 4 + rg;
        float v = tanhf(acc[i][j][rg] + bav) * gv;
        abuf[(size_t)c * 131072 + (size_t)row * 512 + gc] = (_Float16)v;
      }
    }
}

// ---------------- agg: y = mean_c(abuf); out[:,t,:]; xq_next = f16(xs[t+1] + 0.3 y) ----------------
__global__ __launch_bounds__(256) void k_agg(const _Float16* __restrict__ abuf,
                                             const _Float16* __restrict__ xs_h,
                                             _Float16* __restrict__ xq,
                                             float* __restrict__ out, int t) {
  int idx = blockIdx.x * 256 + threadIdx.x;  // < B*H/4
  int i4 = idx * 4;
  float s[4] = {0.0f, 0.0f, 0.0f, 0.0f};
#pragma unroll
  for (int c = 0; c < 16; ++c) {
    f16x4 a = *(const f16x4*)&abuf[(size_t)c * 131072 + i4];
#pragma unroll
    for (int j = 0; j < 4; ++j) s[j] += (float)a[j];
  }
  int b = i4 >> 9, h = i4 & 511;
  float4 y4;
  float* yp = &y4.x;
#pragma unroll
  for (int j = 0; j < 4; ++j) yp[j] = s[j] * (1.0f / 16.0f);
  *(float4*)&out[((size_t)b * T + t) * 512 + h] = y4;
  if (t + 1 < T) {
    f16x4 xs4 = *(const f16x4*)&xs_h[(size_t)(t + 1) * 131072 + i4];
    f16x4 xn;
#pragma unroll
    for (int j = 0; j < 4; ++j) xn[j] = (_Float16)((float)xs4[j] + 0.3f * yp[j]);
    *(f16x4*)&xq[i4] = xn;
  }
}

extern "C" void kernel_launch(void* const* d_in, const int* in_sizes, int n_in,
                              void* d_out, int out_size, void* d_ws, size_t ws_size,
                              hipStream_t stream) {
  const int* tokens = (const int*)d_in[0];
  const float* emb = (const float*)d_in[1];
  const float* Wproj = (const float*)d_in[2];
  const float* bproj = (const float*)d_in[3];
  const float* Wp = (const float*)d_in[4];
  const float* bp = (const float*)d_in[5];
  const float* ln_g = (const float*)d_in[6];
  const float* ln_b = (const float*)d_in[7];
  const float* Wih = (const float*)d_in[8];
  const float* bih = (const float*)d_in[9];
  const float* Whh = (const float*)d_in[10];
  const float* bhh = (const float*)d_in[11];
  const float* Wa = (const float*)d_in[12];
  const float* ba = (const float*)d_in[13];
  const float* gl = (const float*)d_in[14];
  float* out = (float*)d_out;

  char* w8 = (char*)d_ws;
  _Float16* xs_h = (_Float16*)w8;                        // 33,554,432 B
  _Float16* Aq0 = (_Float16*)(w8 + 33554432);            // 16,777,216 B  [c][256][1024] P|h
  _Float16* Aq1 = (_Float16*)(w8 + 50331648);            // 16,777,216 B  ping-pong
  float* cbuf = (float*)(w8 + 67108864);                 //  8,388,608 B
  _Float16* abuf = (_Float16*)(w8 + 75497472);           //  4,194,304 B
  _Float16* xq = (_Float16*)(w8 + 79691776);             //    262,144 B
  _Float16* WpT = (_Float16*)(w8 + 79953920);            //  8,388,608 B
  _Float16* WaT = (_Float16*)(w8 + 88342528);            //  8,388,608 B
  _Float16* WgT = (_Float16*)(w8 + 96731136);            // 67,108,864 B
  float* bsum = (float*)(w8 + 163840000);                //    131,072 B (end 163,971,072)

  hipMemsetAsync(Aq0, 0, 16777216, stream);  // h0 = 0 (step 0 reads Aq0 h-region)
  hipMemsetAsync(cbuf, 0, 8388608, stream);  // c0 = 0

  k_cvt_wg<<<4096, 256, 0, stream>>>(Wih, Whh, WgT);
  k_cvt_tr<<<dim3(8, 8, 16), 256, 0, stream>>>(Wp, WpT);
  k_cvt_tr<<<dim3(8, 8, 16), 256, 0, stream>>>(Wa, WaT);
  k_bias<<<128, 256, 0, stream>>>(bih, bhh, bsum);
  k_emb<<<T * B / 16, 256, 0, stream>>>(tokens, emb, Wproj, bproj, xs_h);
  hipMemcpyAsync(xq, xs_h, 262144, hipMemcpyDeviceToDevice, stream);  // x0 (ext=0)

  for (int t = 0; t < T; ++t) {
    _Float16* Ac = (t & 1) ? Aq1 : Aq0;  // P written here; holds h from t-1
    _Float16* An = (t & 1) ? Aq0 : Aq1;  // new h written here
    k_pln<<<dim3(8, 16), 256, 0, stream>>>(xq, WpT, bp, ln_g, ln_b, Ac);
    k_gates<<<dim3(16, 2, 16), 256, 0, stream>>>(Ac, WgT, bsum, cbuf, An);
    k_assoc<<<dim3(4, 4, 16), 256, 0, stream>>>(An, WaT, ba, gl, abuf);
    k_agg<<<128, 256, 0, stream>>>(abuf, xs_h, xq, out, t);
  }
}

// Round 7
// 7816.342 us; speedup vs baseline: 1.5386x; 1.0790x over previous
//
#include <hip/hip_runtime.h>
#include <hip/hip_bf16.h>

#define V 50257
#define E 256
#define H 512
#define C 16
#define B 256
#define T 128

typedef _Float16 f16x8 __attribute__((ext_vector_type(8)));
typedef _Float16 f16x4 __attribute__((ext_vector_type(4)));
typedef float f32x4 __attribute__((ext_vector_type(4)));

__device__ __forceinline__ float sigm(float x) { return 1.0f / (1.0f + __expf(-x)); }

__device__ __forceinline__ void gload16(const _Float16* g, _Float16* l) {
  __builtin_amdgcn_global_load_lds((const __attribute__((address_space(1))) unsigned*)g,
                                   (__attribute__((address_space(3))) unsigned*)l, 16, 0, 0);
}

// ---------------- one-time: xs_h[t*B+b][:] = f16(emb[tokens[b][t]] @ Wproj + bproj) ----------------
__global__ __launch_bounds__(256) void k_emb(const int* __restrict__ tokens,
                                             const float* __restrict__ emb,
                                             const float* __restrict__ Wproj,
                                             const float* __restrict__ bproj,
                                             _Float16* __restrict__ xs_h) {
  __shared__ float elds[16][256];
  const int tid = threadIdx.x;
  const int r0 = blockIdx.x * 16;  // row r = t*B + b
#pragma unroll
  for (int i = 0; i < 16; ++i) {
    int r = r0 + i;
    int t = r >> 8, b = r & 255;
    int tok = tokens[b * T + t];
    elds[i][tid] = (tok == 0) ? 0.0f : emb[(size_t)tok * E + tid];  // padding_idx=0
  }
  __syncthreads();
  float acc0[16], acc1[16];
#pragma unroll
  for (int i = 0; i < 16; ++i) { acc0[i] = 0.0f; acc1[i] = 0.0f; }
  for (int k = 0; k < E; k += 4) {
    float w0[4], w1[4];
#pragma unroll
    for (int kk = 0; kk < 4; ++kk) {
      w0[kk] = Wproj[(k + kk) * H + tid];
      w1[kk] = Wproj[(k + kk) * H + tid + 256];
    }
#pragma unroll
    for (int i = 0; i < 16; ++i) {
      float4 e4 = *(const float4*)&elds[i][k];
      acc0[i] = fmaf(e4.x, w0[0], acc0[i]);
      acc0[i] = fmaf(e4.y, w0[1], acc0[i]);
      acc0[i] = fmaf(e4.z, w0[2], acc0[i]);
      acc0[i] = fmaf(e4.w, w0[3], acc0[i]);
      acc1[i] = fmaf(e4.x, w1[0], acc1[i]);
      acc1[i] = fmaf(e4.y, w1[1], acc1[i]);
      acc1[i] = fmaf(e4.z, w1[2], acc1[i]);
      acc1[i] = fmaf(e4.w, w1[3], acc1[i]);
    }
  }
  float bp0 = bproj[tid], bp1 = bproj[tid + 256];
#pragma unroll
  for (int i = 0; i < 16; ++i) {
    size_t r = (size_t)(r0 + i);
    xs_h[r * H + tid] = (_Float16)(acc0[i] + bp0);
    xs_h[r * H + tid + 256] = (_Float16)(acc1[i] + bp1);
  }
}

// ---------------- weight prep (once per call) ----------------
// Gate-interleaved layout: n' = (hh>>4)*64 + gate*16 + (hh&15); k2<512 -> Wih, else Whh.
__global__ __launch_bounds__(256) void k_cvt_wg(const float* __restrict__ Wih,
                                                const float* __restrict__ Whh,
                                                _Float16* __restrict__ WgT) {
  for (size_t i4 = ((size_t)blockIdx.x * 256 + threadIdx.x) * 4; i4 < (size_t)33554432;
       i4 += (size_t)gridDim.x * 1024) {
    size_t c = i4 >> 21;
    size_t rem = i4 & 2097151;
    size_t np = rem >> 10;  // n' 0..2047
    size_t k2 = rem & 1023;
    int gate = (int)((np >> 4) & 3);
    int hh = (int)(((np >> 6) << 4) | (np & 15));
    size_t n = (size_t)gate * 512 + hh;
    const float* src = (k2 < 512) ? (Wih + (c * 2048 + n) * 512 + k2)
                                  : (Whh + (c * 2048 + n) * 512 + (k2 - 512));
    float4 v = *(const float4*)src;
    f16x4 o;
    o[0] = (_Float16)v.x; o[1] = (_Float16)v.y; o[2] = (_Float16)v.z; o[3] = (_Float16)v.w;
    *(f16x4*)&WgT[i4] = o;
  }
}

// transpose [c][k][n] f32 -> [c][n][k] f16 (512x512 per c)
__global__ __launch_bounds__(256) void k_cvt_tr(const float* __restrict__ W,
                                                _Float16* __restrict__ WT) {
  __shared__ float tl[64][65];
  const int tid = threadIdx.x;
  const int c = blockIdx.z;
  const int k0 = blockIdx.y * 64, n0 = blockIdx.x * 64;
  const float* Wc = W + (size_t)c * 262144;
#pragma unroll
  for (int q = 0; q < 16; ++q) {
    int idx = q * 256 + tid;
    int r = idx >> 6, cc = idx & 63;
    tl[r][cc] = Wc[(size_t)(k0 + r) * 512 + n0 + cc];
  }
  __syncthreads();
  _Float16* WTc = WT + (size_t)c * 262144;
#pragma unroll
  for (int q = 0; q < 16; ++q) {
    int idx = q * 256 + tid;
    int rr = idx >> 6, cc = idx & 63;
    WTc[(size_t)(n0 + rr) * 512 + k0 + cc] = (_Float16)tl[cc][rr];
  }
}

// bsum in interleaved n' layout
__global__ __launch_bounds__(256) void k_bias(const float* __restrict__ bih,
                                              const float* __restrict__ bhh,
                                              float* __restrict__ bsum) {
  int i = blockIdx.x * 256 + threadIdx.x;
  if (i < C * 4 * H) {
    int c = i >> 11, np = i & 2047;
    int gate = (np >> 4) & 3;
    int hh = ((np >> 6) << 4) | (np & 15);
    int n = gate * 512 + hh;
    bsum[i] = bih[c * 2048 + n] + bhh[c * 2048 + n];
  }
}

// ---------------- percept + LN fused: 32x512 tile per block, K=512 ----------------
// grid 128 (1-D): c = blk&15 (XCD-affine), mt = blk>>4. A = xq (global, prefetched); B = WpT[c].
__global__ __launch_bounds__(256, 2) void k_pln(const _Float16* __restrict__ xq,
                                                const _Float16* __restrict__ WpT,
                                                const float* __restrict__ bp,
                                                const float* __restrict__ ln_g,
                                                const float* __restrict__ ln_b,
                                                _Float16* __restrict__ Pdst) {
  __shared__ _Float16 Bsl[512 * 64];  // 64 KB
  const int tid = threadIdx.x;
  const int w = tid >> 6, l = tid & 63;
  const int blk = blockIdx.x;
  const int c = blk & 15;   // XCD = blk%8 = c%8 -> WpT[c] stays in one XCD's L2
  const int mt = blk >> 4;  // 0..7
  const int m0 = mt * 32;
  const _Float16* Bb = WpT + (size_t)c * 262144;
  const int srow = l >> 3, sj = l & 7;
  const int lm = l & 15, lk = l >> 4;
  f32x4 acc[2][8];
#pragma unroll
  for (int i = 0; i < 2; ++i)
#pragma unroll
    for (int j = 0; j < 8; ++j) acc[i][j] = (f32x4)0.0f;
  const _Float16* pA0 = xq + (size_t)(m0 + lm) * 512 + lk * 8;
  const _Float16* pA1 = pA0 + 16 * 512;
  f16x8 a0s0 = *(const f16x8*)pA0;
  f16x8 a0s1 = *(const f16x8*)(pA0 + 32);
  f16x8 a1s0 = *(const f16x8*)pA1;
  f16x8 a1s1 = *(const f16x8*)(pA1 + 32);
#pragma unroll 1
  for (int kb = 0; kb < 8; ++kb) {
#pragma unroll
    for (int q = 0; q < 16; ++q) {
      int r = q * 32 + w * 8 + srow;
      int gj = sj ^ (r & 7);
      gload16(Bb + (size_t)r * 512 + kb * 64 + gj * 8, &Bsl[(q * 32 + w * 8) * 64]);
    }
    f16x8 u00 = a0s0, u01 = a0s1, u10 = a1s0, u11 = a1s1;
    if (kb < 7) {
      a0s0 = *(const f16x8*)(pA0 + (kb + 1) * 64);
      a0s1 = *(const f16x8*)(pA0 + (kb + 1) * 64 + 32);
      a1s0 = *(const f16x8*)(pA1 + (kb + 1) * 64);
      a1s1 = *(const f16x8*)(pA1 + (kb + 1) * 64 + 32);
    }
    __syncthreads();
#pragma unroll
    for (int s2 = 0; s2 < 2; ++s2) {
      f16x8 bf[8];
#pragma unroll
      for (int j = 0; j < 8; ++j) {
        int RN = w * 128 + j * 16 + lm;
        int pn = (s2 * 4 + lk) ^ (RN & 7);
        bf[j] = *(const f16x8*)&Bsl[RN * 64 + pn * 8];
      }
      f16x8 ua = s2 ? u01 : u00;
      f16x8 ub = s2 ? u11 : u10;
#pragma unroll
      for (int j = 0; j < 8; ++j) {
        acc[0][j] = __builtin_amdgcn_mfma_f32_16x16x32_f16(ua, bf[j], acc[0][j], 0, 0, 0);
        acc[1][j] = __builtin_amdgcn_mfma_f32_16x16x32_f16(ub, bf[j], acc[1][j], 0, 0, 0);
      }
    }
    __syncthreads();
  }
  // epilogue: bias + relu + LN over full 512-col rows
  float bv[8], gcol[8], bcol[8];
#pragma unroll
  for (int j = 0; j < 8; ++j) {
    int col = w * 128 + j * 16 + lm;
    bv[j] = bp[c * 512 + col];
    gcol[j] = ln_g[c * 512 + col];
    bcol[j] = ln_b[c * 512 + col];
  }
  float vals[2][8][4];
  float s1l[2][4], s2l[2][4];
#pragma unroll
  for (int i = 0; i < 2; ++i)
#pragma unroll
    for (int rg = 0; rg < 4; ++rg) { s1l[i][rg] = 0.0f; s2l[i][rg] = 0.0f; }
#pragma unroll
  for (int i = 0; i < 2; ++i)
#pragma unroll
    for (int j = 0; j < 8; ++j)
#pragma unroll
      for (int rg = 0; rg < 4; ++rg) {
        float v = fmaxf(acc[i][j][rg] + bv[j], 0.0f);
        vals[i][j][rg] = v;
        s1l[i][rg] += v;
        s2l[i][rg] += v * v;
      }
#pragma unroll
  for (int m = 1; m < 16; m <<= 1) {
#pragma unroll
    for (int i = 0; i < 2; ++i)
#pragma unroll
      for (int rg = 0; rg < 4; ++rg) {
        s1l[i][rg] += __shfl_xor(s1l[i][rg], m, 64);
        s2l[i][rg] += __shfl_xor(s2l[i][rg], m, 64);
      }
  }
  float* st = (float*)Bsl;  // reuse LDS for stats [w][32 rows][2]
  if (lm == 0) {
#pragma unroll
    for (int i = 0; i < 2; ++i)
#pragma unroll
      for (int rg = 0; rg < 4; ++rg) {
        int row = i * 16 + lk * 4 + rg;
        st[(w * 32 + row) * 2] = s1l[i][rg];
        st[(w * 32 + row) * 2 + 1] = s2l[i][rg];
      }
  }
  __syncthreads();
  float mu_[2][4], rs_[2][4];
#pragma unroll
  for (int i = 0; i < 2; ++i)
#pragma unroll
    for (int rg = 0; rg < 4; ++rg) {
      int row = i * 16 + lk * 4 + rg;
      float t1 = 0.0f, t2 = 0.0f;
#pragma unroll
      for (int ww = 0; ww < 4; ++ww) {
        t1 += st[(ww * 32 + row) * 2];
        t2 += st[(ww * 32 + row) * 2 + 1];
      }
      float mu = t1 * (1.0f / 512.0f);
      float var = t2 * (1.0f / 512.0f) - mu * mu;
      mu_[i][rg] = mu;
      rs_[i][rg] = rsqrtf(var + 1e-5f);
    }
#pragma unroll
  for (int i = 0; i < 2; ++i)
#pragma unroll
    for (int j = 0; j < 8; ++j) {
      int col = w * 128 + j * 16 + lm;
#pragma unroll
      for (int rg = 0; rg < 4; ++rg) {
        int row = i * 16 + lk * 4 + rg;
        float o = (vals[i][j][rg] - mu_[i][rg]) * rs_[i][rg] * gcol[j] + bcol[j];
        Pdst[((size_t)c * 256 + m0 + row) * 1024 + col] = (_Float16)o;
      }
    }
}

// ---------------- gates + LSTM fused: 256x64 tile (B read ONCE), K=1024 ----------------
// grid 512 (1-D): c = blk&15 (XCD-affine: A-tiles L2-resident), nt = blk>>4 (0..31).
__global__ __launch_bounds__(256, 2) void k_gates(const _Float16* __restrict__ A,
                                                  const _Float16* __restrict__ Bm,
                                                  const float* __restrict__ bias,
                                                  float* __restrict__ cstate,
                                                  _Float16* __restrict__ hdst) {
  __shared__ _Float16 Asl[256 * 64];  // 32 KB
  __shared__ _Float16 Bsl[64 * 64];   // 8 KB
  const int tid = threadIdx.x;
  const int w = tid >> 6, l = tid & 63;
  const int blk = blockIdx.x;
  const int c = blk & 15;
  const int n0 = (blk >> 4) * 64;  // 0..1984
  const _Float16* Ab = A + (size_t)c * 262144;
  const _Float16* Bb = Bm + (size_t)c * 2097152 + (size_t)n0 * 1024;
  f32x4 acc[4][4];
#pragma unroll
  for (int i = 0; i < 4; ++i)
#pragma unroll
    for (int j = 0; j < 4; ++j) acc[i][j] = (f32x4)0.0f;
  const int wm = w * 64;  // wave owns rows [wm, wm+64), all 64 cols
  const int srow = l >> 3, sj = l & 7;
  const int lm = l & 15, lk = l >> 4;
#pragma unroll 1
  for (int kb = 0; kb < 16; ++kb) {
    // stage A 256x64 (8 issues/thread), B 64x64 (2 issues/thread); swizzled source
#pragma unroll
    for (int q = 0; q < 8; ++q) {
      int r = w * 64 + q * 8 + srow;
      int gj = sj ^ (r & 7);
      gload16(Ab + (size_t)r * 1024 + kb * 64 + gj * 8, &Asl[(w * 64 + q * 8) * 64]);
    }
#pragma unroll
    for (int q = 0; q < 2; ++q) {
      int r = w * 16 + q * 8 + srow;
      int gj = sj ^ (r & 7);
      gload16(Bb + (size_t)r * 1024 + kb * 64 + gj * 8, &Bsl[(w * 16 + q * 8) * 64]);
    }
    __syncthreads();
#pragma unroll
    for (int s2 = 0; s2 < 2; ++s2) {
      f16x8 af[4], bf[4];
#pragma unroll
      for (int i = 0; i < 4; ++i) {
        int R = wm + i * 16 + lm;
        int p = (s2 * 4 + lk) ^ (R & 7);
        af[i] = *(const f16x8*)&Asl[R * 64 + p * 8];
      }
#pragma unroll
      for (int j = 0; j < 4; ++j) {
        int RN = j * 16 + lm;
        int pn = (s2 * 4 + lk) ^ (RN & 7);
        bf[j] = *(const f16x8*)&Bsl[RN * 64 + pn * 8];
      }
#pragma unroll
      for (int i = 0; i < 4; ++i)
#pragma unroll
        for (int j = 0; j < 4; ++j)
          acc[i][j] = __builtin_amdgcn_mfma_f32_16x16x32_f16(af[i], bf[j], acc[i][j], 0, 0, 0);
    }
    __syncthreads();
  }
  const int rl = lk * 4, cl = lm;
  // columns n' = n0 + j*16 + cl : gate j of h-index hh (n0 is 64-aligned)
  const int hh = ((n0 >> 6) << 4) + cl;
  float bv[4];
#pragma unroll
  for (int j = 0; j < 4; ++j) bv[j] = bias[(size_t)c * 2048 + n0 + j * 16 + cl];
#pragma unroll
  for (int i = 0; i < 4; ++i) {
#pragma unroll
    for (int rg = 0; rg < 4; ++rg) {
      int row = wm + i * 16 + rl + rg;
      float ig = acc[i][0][rg] + bv[0];
      float fg = acc[i][1][rg] + bv[1];
      float gg = acc[i][2][rg] + bv[2];
      float og = acc[i][3][rg] + bv[3];
      size_t ci = ((size_t)c * 256 + row) * 512 + hh;
      float cn = sigm(fg) * cstate[ci] + sigm(ig) * tanhf(gg);
      cstate[ci] = cn;
      hdst[((size_t)c * 256 + row) * 1024 + 512 + hh] = (_Float16)(sigm(og) * tanhf(cn));
    }
  }
}

// ---------------- assoc: 64x128 tile, plain epilogue ----------------
// grid 256 (1-D): c = blk&15 (XCD-affine), r = blk>>4: nt = r&3, mt = r>>2.
__global__ __launch_bounds__(256, 2) void k_assoc(const _Float16* __restrict__ An,
                                                  const _Float16* __restrict__ WaT,
                                                  const float* __restrict__ ba,
                                                  const float* __restrict__ gl,
                                                  _Float16* __restrict__ abuf) {
  __shared__ _Float16 Asl[64 * 64];
  __shared__ _Float16 Bsl[128 * 64];
  const int tid = threadIdx.x;
  const int w = tid >> 6, l = tid & 63;
  const int blk = blockIdx.x;
  const int c = blk & 15;
  const int r_ = blk >> 4;
  const int nt = r_ & 3, mt = r_ >> 2;
  const int n0 = nt * 128;
  const _Float16* Ab = An + 512 + ((size_t)c * 256 + mt * 64) * 1024;
  const _Float16* Bb = WaT + (size_t)c * 262144 + (size_t)n0 * 512;
  f32x4 acc[2][4];
#pragma unroll
  for (int i = 0; i < 2; ++i)
#pragma unroll
    for (int j = 0; j < 4; ++j) acc[i][j] = (f32x4)0.0f;
  const int wm = (w >> 1) * 32, wn = (w & 1) * 64;
  const int srow = l >> 3, sj = l & 7;
  const int lm = l & 15, lk = l >> 4;
#pragma unroll 1
  for (int kb = 0; kb < 8; ++kb) {
#pragma unroll
    for (int q = 0; q < 2; ++q) {
      int r = q * 32 + w * 8 + srow;
      int gj = sj ^ (r & 7);
      gload16(Ab + (size_t)r * 1024 + kb * 64 + gj * 8, &Asl[(q * 32 + w * 8) * 64]);
    }
#pragma unroll
    for (int q = 0; q < 4; ++q) {
      int r = q * 32 + w * 8 + srow;
      int gj = sj ^ (r & 7);
      gload16(Bb + (size_t)r * 512 + kb * 64 + gj * 8, &Bsl[(q * 32 + w * 8) * 64]);
    }
    __syncthreads();
#pragma unroll
    for (int s2 = 0; s2 < 2; ++s2) {
      f16x8 af[2], bf[4];
#pragma unroll
      for (int i = 0; i < 2; ++i) {
        int R = wm + i * 16 + lm;
        int p = (s2 * 4 + lk) ^ (R & 7);
        af[i] = *(const f16x8*)&Asl[R * 64 + p * 8];
      }
#pragma unroll
      for (int j = 0; j < 4; ++j) {
        int RN = wn + j * 16 + lm;
        int pn = (s2 * 4 + lk) ^ (RN & 7);
        bf[j] = *(const f16x8*)&Bsl[RN * 64 + pn * 8];
      }
#pragma unroll
      for (int i = 0; i < 2; ++i)
#pragma unroll
        for (int j = 0; j < 4; ++j)
          acc[i][j] = __builtin_amdgcn_mfma_f32_16x16x32_f16(af[i], bf[j], acc[i][j], 0, 0, 0);
    }
    __syncthreads();
  }
  float gv = sigm(gl[c]);
#pragma unroll
  for (int i = 0; i < 2; ++i)
#pragma unroll
    for (int j = 0; j < 4; ++j) {
      int gc = n0 + wn + j * 16 + lm;
      float bav = ba[c * 512 + gc];
#pragma unroll
      for (int rg = 0; rg < 4; ++rg) {
        int row = mt * 64 + wm + i * 16 + lk * 4 + rg;
        float v = tanhf(acc[i][j][rg] + bav) * gv;
        abuf[(size_t)c * 131072 + (size_t)row * 512 + gc] = (_Float16)v;
      }
    }
}

// ---------------- agg: y = mean_c(abuf); out[:,t,:]; xq_next = f16(xs[t+1] + 0.3 y) ----------------
__global__ __launch_bounds__(256) void k_agg(const _Float16* __restrict__ abuf,
                                             const _Float16* __restrict__ xs_h,
                                             _Float16* __restrict__ xq,
                                             float* __restrict__ out, int t) {
  int idx = blockIdx.x * 256 + threadIdx.x;  // < B*H/4
  int i4 = idx * 4;
  float s[4] = {0.0f, 0.0f, 0.0f, 0.0f};
#pragma unroll
  for (int c = 0; c < 16; ++c) {
    f16x4 a = *(const f16x4*)&abuf[(size_t)c * 131072 + i4];
#pragma unroll
    for (int j = 0; j < 4; ++j) s[j] += (float)a[j];
  }
  int b = i4 >> 9, h = i4 & 511;
  float4 y4;
  float* yp = &y4.x;
#pragma unroll
  for (int j = 0; j < 4; ++j) yp[j] = s[j] * (1.0f / 16.0f);
  *(float4*)&out[((size_t)b * T + t) * 512 + h] = y4;
  if (t + 1 < T) {
    f16x4 xs4 = *(const f16x4*)&xs_h[(size_t)(t + 1) * 131072 + i4];
    f16x4 xn;
#pragma unroll
    for (int j = 0; j < 4; ++j) xn[j] = (_Float16)((float)xs4[j] + 0.3f * yp[j]);
    *(f16x4*)&xq[i4] = xn;
  }
}

extern "C" void kernel_launch(void* const* d_in, const int* in_sizes, int n_in,
                              void* d_out, int out_size, void* d_ws, size_t ws_size,
                              hipStream_t stream) {
  const int* tokens = (const int*)d_in[0];
  const float* emb = (const float*)d_in[1];
  const float* Wproj = (const float*)d_in[2];
  const float* bproj = (const float*)d_in[3];
  const float* Wp = (const float*)d_in[4];
  const float* bp = (const float*)d_in[5];
  const float* ln_g = (const float*)d_in[6];
  const float* ln_b = (const float*)d_in[7];
  const float* Wih = (const float*)d_in[8];
  const float* bih = (const float*)d_in[9];
  const float* Whh = (const float*)d_in[10];
  const float* bhh = (const float*)d_in[11];
  const float* Wa = (const float*)d_in[12];
  const float* ba = (const float*)d_in[13];
  const float* gl = (const float*)d_in[14];
  float* out = (float*)d_out;

  char* w8 = (char*)d_ws;
  _Float16* xs_h = (_Float16*)w8;                        // 33,554,432 B
  _Float16* Aq0 = (_Float16*)(w8 + 33554432);            // 16,777,216 B  [c][256][1024] P|h
  _Float16* Aq1 = (_Float16*)(w8 + 50331648);            // 16,777,216 B  ping-pong
  float* cbuf = (float*)(w8 + 67108864);                 //  8,388,608 B
  _Float16* abuf = (_Float16*)(w8 + 75497472);           //  4,194,304 B
  _Float16* xq = (_Float16*)(w8 + 79691776);             //    262,144 B
  _Float16* WpT = (_Float16*)(w8 + 79953920);            //  8,388,608 B
  _Float16* WaT = (_Float16*)(w8 + 88342528);            //  8,388,608 B
  _Float16* WgT = (_Float16*)(w8 + 96731136);            // 67,108,864 B
  float* bsum = (float*)(w8 + 163840000);                //    131,072 B (end 163,971,072)

  hipMemsetAsync(Aq0, 0, 16777216, stream);  // h0 = 0 (step 0 reads Aq0 h-region)
  hipMemsetAsync(cbuf, 0, 8388608, stream);  // c0 = 0

  k_cvt_wg<<<4096, 256, 0, stream>>>(Wih, Whh, WgT);
  k_cvt_tr<<<dim3(8, 8, 16), 256, 0, stream>>>(Wp, WpT);
  k_cvt_tr<<<dim3(8, 8, 16), 256, 0, stream>>>(Wa, WaT);
  k_bias<<<128, 256, 0, stream>>>(bih, bhh, bsum);
  k_emb<<<T * B / 16, 256, 0, stream>>>(tokens, emb, Wproj, bproj, xs_h);
  hipMemcpyAsync(xq, xs_h, 262144, hipMemcpyDeviceToDevice, stream);  // x0 (ext=0)

  for (int t = 0; t < T; ++t) {
    _Float16* Ac = (t & 1) ? Aq1 : Aq0;  // P written here; holds h from t-1
    _Float16* An = (t & 1) ? Aq0 : Aq1;  // new h written here
    k_pln<<<128, 256, 0, stream>>>(xq, WpT, bp, ln_g, ln_b, Ac);
    k_gates<<<512, 256, 0, stream>>>(Ac, WgT, bsum, cbuf, An);
    k_assoc<<<256, 256, 0, stream>>>(An, WaT, ba, gl, abuf);
    k_agg<<<128, 256, 0, stream>>>(abuf, xs_h, xq, out, t);
  }
}

// Round 8
// 7611.136 us; speedup vs baseline: 1.5801x; 1.0270x over previous
//
#include <hip/hip_runtime.h>
#include <hip/hip_bf16.h>

#define V 50257
#define E 256
#define H 512
#define C 16
#define B 256
#define T 128

typedef _Float16 f16x8 __attribute__((ext_vector_type(8)));
typedef _Float16 f16x4 __attribute__((ext_vector_type(4)));
typedef float f32x4 __attribute__((ext_vector_type(4)));

__device__ __forceinline__ float sigm(float x) { return 1.0f / (1.0f + __expf(-x)); }

__device__ __forceinline__ void gload16(const _Float16* g, _Float16* l) {
  __builtin_amdgcn_global_load_lds((const __attribute__((address_space(1))) unsigned*)g,
                                   (__attribute__((address_space(3))) unsigned*)l, 16, 0, 0);
}

// ---------------- one-time: xs_h[t*B+b][:] = f16(emb[tokens[b][t]] @ Wproj + bproj) ----------------
__global__ __launch_bounds__(256) void k_emb(const int* __restrict__ tokens,
                                             const float* __restrict__ emb,
                                             const float* __restrict__ Wproj,
                                             const float* __restrict__ bproj,
                                             _Float16* __restrict__ xs_h) {
  __shared__ float elds[16][256];
  const int tid = threadIdx.x;
  const int r0 = blockIdx.x * 16;  // row r = t*B + b
#pragma unroll
  for (int i = 0; i < 16; ++i) {
    int r = r0 + i;
    int t = r >> 8, b = r & 255;
    int tok = tokens[b * T + t];
    elds[i][tid] = (tok == 0) ? 0.0f : emb[(size_t)tok * E + tid];  // padding_idx=0
  }
  __syncthreads();
  float acc0[16], acc1[16];
#pragma unroll
  for (int i = 0; i < 16; ++i) { acc0[i] = 0.0f; acc1[i] = 0.0f; }
  for (int k = 0; k < E; k += 4) {
    float w0[4], w1[4];
#pragma unroll
    for (int kk = 0; kk < 4; ++kk) {
      w0[kk] = Wproj[(k + kk) * H + tid];
      w1[kk] = Wproj[(k + kk) * H + tid + 256];
    }
#pragma unroll
    for (int i = 0; i < 16; ++i) {
      float4 e4 = *(const float4*)&elds[i][k];
      acc0[i] = fmaf(e4.x, w0[0], acc0[i]);
      acc0[i] = fmaf(e4.y, w0[1], acc0[i]);
      acc0[i] = fmaf(e4.z, w0[2], acc0[i]);
      acc0[i] = fmaf(e4.w, w0[3], acc0[i]);
      acc1[i] = fmaf(e4.x, w1[0], acc1[i]);
      acc1[i] = fmaf(e4.y, w1[1], acc1[i]);
      acc1[i] = fmaf(e4.z, w1[2], acc1[i]);
      acc1[i] = fmaf(e4.w, w1[3], acc1[i]);
    }
  }
  float bp0 = bproj[tid], bp1 = bproj[tid + 256];
#pragma unroll
  for (int i = 0; i < 16; ++i) {
    size_t r = (size_t)(r0 + i);
    xs_h[r * H + tid] = (_Float16)(acc0[i] + bp0);
    xs_h[r * H + tid + 256] = (_Float16)(acc1[i] + bp1);
  }
}

// ---------------- weight prep (once per call) ----------------
// Gate-interleaved layout: n' = (hh>>4)*64 + gate*16 + (hh&15); k2<512 -> Wih, else Whh.
__global__ __launch_bounds__(256) void k_cvt_wg(const float* __restrict__ Wih,
                                                const float* __restrict__ Whh,
                                                _Float16* __restrict__ WgT) {
  for (size_t i4 = ((size_t)blockIdx.x * 256 + threadIdx.x) * 4; i4 < (size_t)33554432;
       i4 += (size_t)gridDim.x * 1024) {
    size_t c = i4 >> 21;
    size_t rem = i4 & 2097151;
    size_t np = rem >> 10;  // n' 0..2047
    size_t k2 = rem & 1023;
    int gate = (int)((np >> 4) & 3);
    int hh = (int)(((np >> 6) << 4) | (np & 15));
    size_t n = (size_t)gate * 512 + hh;
    const float* src = (k2 < 512) ? (Wih + (c * 2048 + n) * 512 + k2)
                                  : (Whh + (c * 2048 + n) * 512 + (k2 - 512));
    float4 v = *(const float4*)src;
    f16x4 o;
    o[0] = (_Float16)v.x; o[1] = (_Float16)v.y; o[2] = (_Float16)v.z; o[3] = (_Float16)v.w;
    *(f16x4*)&WgT[i4] = o;
  }
}

// transpose [c][k][n] f32 -> [c][n][k] f16 (512x512 per c)
__global__ __launch_bounds__(256) void k_cvt_tr(const float* __restrict__ W,
                                                _Float16* __restrict__ WT) {
  __shared__ float tl[64][65];
  const int tid = threadIdx.x;
  const int c = blockIdx.z;
  const int k0 = blockIdx.y * 64, n0 = blockIdx.x * 64;
  const float* Wc = W + (size_t)c * 262144;
#pragma unroll
  for (int q = 0; q < 16; ++q) {
    int idx = q * 256 + tid;
    int r = idx >> 6, cc = idx & 63;
    tl[r][cc] = Wc[(size_t)(k0 + r) * 512 + n0 + cc];
  }
  __syncthreads();
  _Float16* WTc = WT + (size_t)c * 262144;
#pragma unroll
  for (int q = 0; q < 16; ++q) {
    int idx = q * 256 + tid;
    int rr = idx >> 6, cc = idx & 63;
    WTc[(size_t)(n0 + rr) * 512 + k0 + cc] = (_Float16)tl[cc][rr];
  }
}

// bsum in interleaved n' layout
__global__ __launch_bounds__(256) void k_bias(const float* __restrict__ bih,
                                              const float* __restrict__ bhh,
                                              float* __restrict__ bsum) {
  int i = blockIdx.x * 256 + threadIdx.x;
  if (i < C * 4 * H) {
    int c = i >> 11, np = i & 2047;
    int gate = (np >> 4) & 3;
    int hh = ((np >> 6) << 4) | (np & 15);
    int n = gate * 512 + hh;
    bsum[i] = bih[c * 2048 + n] + bhh[c * 2048 + n];
  }
}

// ---------------- percept + LN fused: 32x512 tile per block, K=512 ----------------
// grid 128 (1-D): c = blk&15 (XCD-affine), mt = blk>>4. A = xq (global, prefetched); B = WpT[c].
__global__ __launch_bounds__(256, 2) void k_pln(const _Float16* __restrict__ xq,
                                                const _Float16* __restrict__ WpT,
                                                const float* __restrict__ bp,
                                                const float* __restrict__ ln_g,
                                                const float* __restrict__ ln_b,
                                                _Float16* __restrict__ Pdst) {
  __shared__ _Float16 Bsl[512 * 64];  // 64 KB
  const int tid = threadIdx.x;
  const int w = tid >> 6, l = tid & 63;
  const int blk = blockIdx.x;
  const int c = blk & 15;   // XCD = blk%8 = c%8 -> WpT[c] stays in one XCD's L2
  const int mt = blk >> 4;  // 0..7
  const int m0 = mt * 32;
  const _Float16* Bb = WpT + (size_t)c * 262144;
  const int srow = l >> 3, sj = l & 7;
  const int lm = l & 15, lk = l >> 4;
  f32x4 acc[2][8];
#pragma unroll
  for (int i = 0; i < 2; ++i)
#pragma unroll
    for (int j = 0; j < 8; ++j) acc[i][j] = (f32x4)0.0f;
  const _Float16* pA0 = xq + (size_t)(m0 + lm) * 512 + lk * 8;
  const _Float16* pA1 = pA0 + 16 * 512;
  f16x8 a0s0 = *(const f16x8*)pA0;
  f16x8 a0s1 = *(const f16x8*)(pA0 + 32);
  f16x8 a1s0 = *(const f16x8*)pA1;
  f16x8 a1s1 = *(const f16x8*)(pA1 + 32);
#pragma unroll 1
  for (int kb = 0; kb < 8; ++kb) {
#pragma unroll
    for (int q = 0; q < 16; ++q) {
      int r = q * 32 + w * 8 + srow;
      int gj = sj ^ (r & 7);
      gload16(Bb + (size_t)r * 512 + kb * 64 + gj * 8, &Bsl[(q * 32 + w * 8) * 64]);
    }
    f16x8 u00 = a0s0, u01 = a0s1, u10 = a1s0, u11 = a1s1;
    if (kb < 7) {
      a0s0 = *(const f16x8*)(pA0 + (kb + 1) * 64);
      a0s1 = *(const f16x8*)(pA0 + (kb + 1) * 64 + 32);
      a1s0 = *(const f16x8*)(pA1 + (kb + 1) * 64);
      a1s1 = *(const f16x8*)(pA1 + (kb + 1) * 64 + 32);
    }
    __syncthreads();
#pragma unroll
    for (int s2 = 0; s2 < 2; ++s2) {
      f16x8 bf[8];
#pragma unroll
      for (int j = 0; j < 8; ++j) {
        int RN = w * 128 + j * 16 + lm;
        int pn = (s2 * 4 + lk) ^ (RN & 7);
        bf[j] = *(const f16x8*)&Bsl[RN * 64 + pn * 8];
      }
      f16x8 ua = s2 ? u01 : u00;
      f16x8 ub = s2 ? u11 : u10;
#pragma unroll
      for (int j = 0; j < 8; ++j) {
        acc[0][j] = __builtin_amdgcn_mfma_f32_16x16x32_f16(ua, bf[j], acc[0][j], 0, 0, 0);
        acc[1][j] = __builtin_amdgcn_mfma_f32_16x16x32_f16(ub, bf[j], acc[1][j], 0, 0, 0);
      }
    }
    __syncthreads();
  }
  // epilogue: bias + relu + LN over full 512-col rows
  float bv[8], gcol[8], bcol[8];
#pragma unroll
  for (int j = 0; j < 8; ++j) {
    int col = w * 128 + j * 16 + lm;
    bv[j] = bp[c * 512 + col];
    gcol[j] = ln_g[c * 512 + col];
    bcol[j] = ln_b[c * 512 + col];
  }
  float vals[2][8][4];
  float s1l[2][4], s2l[2][4];
#pragma unroll
  for (int i = 0; i < 2; ++i)
#pragma unroll
    for (int rg = 0; rg < 4; ++rg) { s1l[i][rg] = 0.0f; s2l[i][rg] = 0.0f; }
#pragma unroll
  for (int i = 0; i < 2; ++i)
#pragma unroll
    for (int j = 0; j < 8; ++j)
#pragma unroll
      for (int rg = 0; rg < 4; ++rg) {
        float v = fmaxf(acc[i][j][rg] + bv[j], 0.0f);
        vals[i][j][rg] = v;
        s1l[i][rg] += v;
        s2l[i][rg] += v * v;
      }
#pragma unroll
  for (int m = 1; m < 16; m <<= 1) {
#pragma unroll
    for (int i = 0; i < 2; ++i)
#pragma unroll
      for (int rg = 0; rg < 4; ++rg) {
        s1l[i][rg] += __shfl_xor(s1l[i][rg], m, 64);
        s2l[i][rg] += __shfl_xor(s2l[i][rg], m, 64);
      }
  }
  float* st = (float*)Bsl;  // reuse LDS for stats [w][32 rows][2]
  if (lm == 0) {
#pragma unroll
    for (int i = 0; i < 2; ++i)
#pragma unroll
      for (int rg = 0; rg < 4; ++rg) {
        int row = i * 16 + lk * 4 + rg;
        st[(w * 32 + row) * 2] = s1l[i][rg];
        st[(w * 32 + row) * 2 + 1] = s2l[i][rg];
      }
  }
  __syncthreads();
  float mu_[2][4], rs_[2][4];
#pragma unroll
  for (int i = 0; i < 2; ++i)
#pragma unroll
    for (int rg = 0; rg < 4; ++rg) {
      int row = i * 16 + lk * 4 + rg;
      float t1 = 0.0f, t2 = 0.0f;
#pragma unroll
      for (int ww = 0; ww < 4; ++ww) {
        t1 += st[(ww * 32 + row) * 2];
        t2 += st[(ww * 32 + row) * 2 + 1];
      }
      float mu = t1 * (1.0f / 512.0f);
      float var = t2 * (1.0f / 512.0f) - mu * mu;
      mu_[i][rg] = mu;
      rs_[i][rg] = rsqrtf(var + 1e-5f);
    }
#pragma unroll
  for (int i = 0; i < 2; ++i)
#pragma unroll
    for (int j = 0; j < 8; ++j) {
      int col = w * 128 + j * 16 + lm;
#pragma unroll
      for (int rg = 0; rg < 4; ++rg) {
        int row = i * 16 + lk * 4 + rg;
        float o = (vals[i][j][rg] - mu_[i][rg]) * rs_[i][rg] * gcol[j] + bcol[j];
        Pdst[((size_t)c * 256 + m0 + row) * 1024 + col] = (_Float16)o;
      }
    }
}

// ---------------- gates + LSTM fused: 256x128 tile, K=1024, counted-vmcnt 3-buf pipeline ----------------
// grid 256 (1-D), 512 threads: c = blk&15 (XCD-affine), nt = blk>>4 (0..15). B read ONCE per step.
__global__ __launch_bounds__(512, 1) void k_gates(const _Float16* __restrict__ A,
                                                  const _Float16* __restrict__ Bm,
                                                  const float* __restrict__ bias,
                                                  float* __restrict__ cstate,
                                                  _Float16* __restrict__ hdst) {
  // 3 buffers x (A 256x64 + B 128x64) f16 = 3 x 48 KB = 144 KB
  __shared__ _Float16 sm[3 * 24576];
  const int tid = threadIdx.x;
  const int w = tid >> 6, l = tid & 63;
  const int blk = blockIdx.x;
  const int c = blk & 15;
  const int n0 = (blk >> 4) * 128;  // 0..1920
  const _Float16* Ab = A + (size_t)c * 262144;
  const _Float16* Bb = Bm + (size_t)c * 2097152 + (size_t)n0 * 1024;
  f32x4 acc[4][4];
#pragma unroll
  for (int i = 0; i < 4; ++i)
#pragma unroll
    for (int j = 0; j < 4; ++j) acc[i][j] = (f32x4)0.0f;
  const int wm = (w >> 1) * 64;  // 4 m-groups of 64 rows
  const int wn = (w & 1) * 64;   // 2 n-groups of 64 cols
  const int srow = l >> 3, sj = l & 7;
  const int lm = l & 15, lk = l >> 4;

  // stage K-tile kb into buffer buf: A rows r cols [kb*64,kb*64+64), B likewise.
  // LDS linear [row][64]; source col-chunk XOR-swizzled (chunk j at j^(r&7)).
  auto STAGE = [&](int buf, int kb) {
    _Float16* As = sm + buf * 24576;
    _Float16* Bs = As + 16384;
#pragma unroll
    for (int q = 0; q < 4; ++q) {
      int rb = q * 64 + w * 8;  // wave-uniform row base
      int r = rb + srow;
      int gj = sj ^ (r & 7);
      gload16(Ab + (size_t)r * 1024 + kb * 64 + gj * 8, &As[rb * 64]);
    }
#pragma unroll
    for (int q = 0; q < 2; ++q) {
      int rb = q * 64 + w * 8;
      int r = rb + srow;
      int gj = sj ^ (r & 7);
      gload16(Bb + (size_t)r * 1024 + kb * 64 + gj * 8, &Bs[rb * 64]);
    }
  };

  STAGE(0, 0);
  STAGE(1, 1);
#pragma unroll 1
  for (int kb = 0; kb < 16; ++kb) {
    const int cur = kb % 3;
    if (kb + 2 < 16) STAGE((kb + 2) % 3, kb + 2);
    // counted wait: only the current tile's 6 loads must have landed;
    // the 12 younger loads stay in flight across the barrier (T4).
    if (kb < 14) {
      asm volatile("s_waitcnt vmcnt(12)" ::: "memory");
    } else if (kb == 14) {
      asm volatile("s_waitcnt vmcnt(6)" ::: "memory");
    } else {
      asm volatile("s_waitcnt vmcnt(0)" ::: "memory");
    }
    __builtin_amdgcn_s_barrier();
    __builtin_amdgcn_sched_barrier(0);
    const _Float16* As = sm + cur * 24576;
    const _Float16* Bs = As + 16384;
#pragma unroll
    for (int s2 = 0; s2 < 2; ++s2) {
      f16x8 af[4], bf[4];
#pragma unroll
      for (int i = 0; i < 4; ++i) {
        int R = wm + i * 16 + lm;
        int p = (s2 * 4 + lk) ^ (R & 7);
        af[i] = *(const f16x8*)&As[R * 64 + p * 8];
        int RN = wn + i * 16 + lm;
        int pn = (s2 * 4 + lk) ^ (RN & 7);
        bf[i] = *(const f16x8*)&Bs[RN * 64 + pn * 8];
      }
#pragma unroll
      for (int i = 0; i < 4; ++i)
#pragma unroll
        for (int j = 0; j < 4; ++j)
          acc[i][j] = __builtin_amdgcn_mfma_f32_16x16x32_f16(af[i], bf[j], acc[i][j], 0, 0, 0);
    }
    asm volatile("s_waitcnt lgkmcnt(0)" ::: "memory");
    __builtin_amdgcn_s_barrier();  // reads of buf[cur] done -> safe to restage next iter
  }
  const int rl = lk * 4, cl = lm;
  // columns n' = (n0+wn) + j*16 + cl : gate j of h-index hh ((n0+wn) is 64-aligned)
  const int hh = (((n0 + wn) >> 6) << 4) + cl;
  float bv[4];
#pragma unroll
  for (int j = 0; j < 4; ++j) bv[j] = bias[(size_t)c * 2048 + (n0 + wn) + j * 16 + cl];
#pragma unroll
  for (int i = 0; i < 4; ++i) {
#pragma unroll
    for (int rg = 0; rg < 4; ++rg) {
      int row = wm + i * 16 + rl + rg;
      float ig = acc[i][0][rg] + bv[0];
      float fg = acc[i][1][rg] + bv[1];
      float gg = acc[i][2][rg] + bv[2];
      float og = acc[i][3][rg] + bv[3];
      size_t ci = ((size_t)c * 256 + row) * 512 + hh;
      float cn = sigm(fg) * cstate[ci] + sigm(ig) * tanhf(gg);
      cstate[ci] = cn;
      hdst[((size_t)c * 256 + row) * 1024 + 512 + hh] = (_Float16)(sigm(og) * tanhf(cn));
    }
  }
}

// ---------------- assoc: 64x128 tile, plain epilogue ----------------
// grid 256 (1-D): c = blk&15 (XCD-affine), r = blk>>4: nt = r&3, mt = r>>2.
__global__ __launch_bounds__(256, 2) void k_assoc(const _Float16* __restrict__ An,
                                                  const _Float16* __restrict__ WaT,
                                                  const float* __restrict__ ba,
                                                  const float* __restrict__ gl,
                                                  _Float16* __restrict__ abuf) {
  __shared__ _Float16 Asl[64 * 64];
  __shared__ _Float16 Bsl[128 * 64];
  const int tid = threadIdx.x;
  const int w = tid >> 6, l = tid & 63;
  const int blk = blockIdx.x;
  const int c = blk & 15;
  const int r_ = blk >> 4;
  const int nt = r_ & 3, mt = r_ >> 2;
  const int n0 = nt * 128;
  const _Float16* Ab = An + 512 + ((size_t)c * 256 + mt * 64) * 1024;
  const _Float16* Bb = WaT + (size_t)c * 262144 + (size_t)n0 * 512;
  f32x4 acc[2][4];
#pragma unroll
  for (int i = 0; i < 2; ++i)
#pragma unroll
    for (int j = 0; j < 4; ++j) acc[i][j] = (f32x4)0.0f;
  const int wm = (w >> 1) * 32, wn = (w & 1) * 64;
  const int srow = l >> 3, sj = l & 7;
  const int lm = l & 15, lk = l >> 4;
#pragma unroll 1
  for (int kb = 0; kb < 8; ++kb) {
#pragma unroll
    for (int q = 0; q < 2; ++q) {
      int r = q * 32 + w * 8 + srow;
      int gj = sj ^ (r & 7);
      gload16(Ab + (size_t)r * 1024 + kb * 64 + gj * 8, &Asl[(q * 32 + w * 8) * 64]);
    }
#pragma unroll
    for (int q = 0; q < 4; ++q) {
      int r = q * 32 + w * 8 + srow;
      int gj = sj ^ (r & 7);
      gload16(Bb + (size_t)r * 512 + kb * 64 + gj * 8, &Bsl[(q * 32 + w * 8) * 64]);
    }
    __syncthreads();
#pragma unroll
    for (int s2 = 0; s2 < 2; ++s2) {
      f16x8 af[2], bf[4];
#pragma unroll
      for (int i = 0; i < 2; ++i) {
        int R = wm + i * 16 + lm;
        int p = (s2 * 4 + lk) ^ (R & 7);
        af[i] = *(const f16x8*)&Asl[R * 64 + p * 8];
      }
#pragma unroll
      for (int j = 0; j < 4; ++j) {
        int RN = wn + j * 16 + lm;
        int pn = (s2 * 4 + lk) ^ (RN & 7);
        bf[j] = *(const f16x8*)&Bsl[RN * 64 + pn * 8];
      }
#pragma unroll
      for (int i = 0; i < 2; ++i)
#pragma unroll
        for (int j = 0; j < 4; ++j)
          acc[i][j] = __builtin_amdgcn_mfma_f32_16x16x32_f16(af[i], bf[j], acc[i][j], 0, 0, 0);
    }
    __syncthreads();
  }
  float gv = sigm(gl[c]);
#pragma unroll
  for (int i = 0; i < 2; ++i)
#pragma unroll
    for (int j = 0; j < 4; ++j) {
      int gc = n0 + wn + j * 16 + lm;
      float bav = ba[c * 512 + gc];
#pragma unroll
      for (int rg = 0; rg < 4; ++rg) {
        int row = mt * 64 + wm + i * 16 + lk * 4 + rg;
        float v = tanhf(acc[i][j][rg] + bav) * gv;
        abuf[(size_t)c * 131072 + (size_t)row * 512 + gc] = (_Float16)v;
      }
    }
}

// ---------------- agg: y = mean_c(abuf); out[:,t,:]; xq_next = f16(xs[t+1] + 0.3 y) ----------------
__global__ __launch_bounds__(256) void k_agg(const _Float16* __restrict__ abuf,
                                             const _Float16* __restrict__ xs_h,
                                             _Float16* __restrict__ xq,
                                             float* __restrict__ out, int t) {
  int idx = blockIdx.x * 256 + threadIdx.x;  // < B*H/4
  int i4 = idx * 4;
  float s[4] = {0.0f, 0.0f, 0.0f, 0.0f};
#pragma unroll
  for (int c = 0; c < 16; ++c) {
    f16x4 a = *(const f16x4*)&abuf[(size_t)c * 131072 + i4];
#pragma unroll
    for (int j = 0; j < 4; ++j) s[j] += (float)a[j];
  }
  int b = i4 >> 9, h = i4 & 511;
  float4 y4;
  float* yp = &y4.x;
#pragma unroll
  for (int j = 0; j < 4; ++j) yp[j] = s[j] * (1.0f / 16.0f);
  *(float4*)&out[((size_t)b * T + t) * 512 + h] = y4;
  if (t + 1 < T) {
    f16x4 xs4 = *(const f16x4*)&xs_h[(size_t)(t + 1) * 131072 + i4];
    f16x4 xn;
#pragma unroll
    for (int j = 0; j < 4; ++j) xn[j] = (_Float16)((float)xs4[j] + 0.3f * yp[j]);
    *(f16x4*)&xq[i4] = xn;
  }
}

extern "C" void kernel_launch(void* const* d_in, const int* in_sizes, int n_in,
                              void* d_out, int out_size, void* d_ws, size_t ws_size,
                              hipStream_t stream) {
  const int* tokens = (const int*)d_in[0];
  const float* emb = (const float*)d_in[1];
  const float* Wproj = (const float*)d_in[2];
  const float* bproj = (const float*)d_in[3];
  const float* Wp = (const float*)d_in[4];
  const float* bp = (const float*)d_in[5];
  const float* ln_g = (const float*)d_in[6];
  const float* ln_b = (const float*)d_in[7];
  const float* Wih = (const float*)d_in[8];
  const float* bih = (const float*)d_in[9];
  const float* Whh = (const float*)d_in[10];
  const float* bhh = (const float*)d_in[11];
  const float* Wa = (const float*)d_in[12];
  const float* ba = (const float*)d_in[13];
  const float* gl = (const float*)d_in[14];
  float* out = (float*)d_out;

  char* w8 = (char*)d_ws;
  _Float16* xs_h = (_Float16*)w8;                        // 33,554,432 B
  _Float16* Aq0 = (_Float16*)(w8 + 33554432);            // 16,777,216 B  [c][256][1024] P|h
  _Float16* Aq1 = (_Float16*)(w8 + 50331648);            // 16,777,216 B  ping-pong
  float* cbuf = (float*)(w8 + 67108864);                 //  8,388,608 B
  _Float16* abuf = (_Float16*)(w8 + 75497472);           //  4,194,304 B
  _Float16* xq = (_Float16*)(w8 + 79691776);             //    262,144 B
  _Float16* WpT = (_Float16*)(w8 + 79953920);            //  8,388,608 B
  _Float16* WaT = (_Float16*)(w8 + 88342528);            //  8,388,608 B
  _Float16* WgT = (_Float16*)(w8 + 96731136);            // 67,108,864 B
  float* bsum = (float*)(w8 + 163840000);                //    131,072 B (end 163,971,072)

  hipMemsetAsync(Aq0, 0, 16777216, stream);  // h0 = 0 (step 0 reads Aq0 h-region)
  hipMemsetAsync(cbuf, 0, 8388608, stream);  // c0 = 0

  k_cvt_wg<<<4096, 256, 0, stream>>>(Wih, Whh, WgT);
  k_cvt_tr<<<dim3(8, 8, 16), 256, 0, stream>>>(Wp, WpT);
  k_cvt_tr<<<dim3(8, 8, 16), 256, 0, stream>>>(Wa, WaT);
  k_bias<<<128, 256, 0, stream>>>(bih, bhh, bsum);
  k_emb<<<T * B / 16, 256, 0, stream>>>(tokens, emb, Wproj, bproj, xs_h);
  hipMemcpyAsync(xq, xs_h, 262144, hipMemcpyDeviceToDevice, stream);  // x0 (ext=0)

  for (int t = 0; t < T; ++t) {
    _Float16* Ac = (t & 1) ? Aq1 : Aq0;  // P written here; holds h from t-1
    _Float16* An = (t & 1) ? Aq0 : Aq1;  // new h written here
    k_pln<<<128, 256, 0, stream>>>(xq, WpT, bp, ln_g, ln_b, Ac);
    k_gates<<<256, 512, 0, stream>>>(Ac, WgT, bsum, cbuf, An);
    k_assoc<<<256, 256, 0, stream>>>(An, WaT, ba, gl, abuf);
    k_agg<<<128, 256, 0, stream>>>(abuf, xs_h, xq, out, t);
  }
}